// Round 1
// 1145.068 us; speedup vs baseline: 2.0769x; 2.0769x over previous
//
#include <hip/hip_runtime.h>
#include <hip/hip_bf16.h>

typedef __hip_bfloat16 bf16;
#define NEG_BIG (-3.0e38f)

// MFMA fragment types (gfx950: v_mfma_f32_16x16x32_bf16 takes <8 x bfloat>)
typedef __bf16 bf16x8 __attribute__((ext_vector_type(8)));
typedef float  f32x4  __attribute__((ext_vector_type(4)));

__device__ inline void load8_f32(const float* p, float* o) {
  float4 a = *reinterpret_cast<const float4*>(p);
  float4 b = *reinterpret_cast<const float4*>(p + 4);
  o[0]=a.x; o[1]=a.y; o[2]=a.z; o[3]=a.w;
  o[4]=b.x; o[5]=b.y; o[6]=b.z; o[7]=b.w;
}
__device__ inline void load8_bf(const bf16* p, float* o) {
  uint4 u = *reinterpret_cast<const uint4*>(p);
  unsigned w[4] = {u.x, u.y, u.z, u.w};
#pragma unroll
  for (int i = 0; i < 4; i++) {
    o[2*i]   = __uint_as_float(w[i] << 16);
    o[2*i+1] = __uint_as_float(w[i] & 0xffff0000u);
  }
}

// ---------- Kernel 1: QKV GEMM  X[8192,1024]f32 @ W[1024,3072]f32 + b ----------
// Q -> ws (bf16 BHSD), K -> d_out[0:16M) (bf16 BHSD), V -> d_out[16M:32M)
// stored TRANSPOSED as bf16 [B,H,D,S] so attention's PV B-fragments are
// contiguous 16B LDS reads (no in-kernel transpose).
__global__ __launch_bounds__(256)
void qkv_f(const float* __restrict__ X, const float* __restrict__ W,
           const float* __restrict__ bias,
           bf16* __restrict__ q, bf16* __restrict__ k, bf16* __restrict__ v)
{
  __shared__ float As[64][33];
  __shared__ float Bs[32][68];
  const int t   = threadIdx.x;
  const int bm  = blockIdx.y, bn = blockIdx.x;     // bn in [0,48)
  const int gm0 = bm * 64, gn0 = bn * 64;
  const int tx  = t & 15, ty = t >> 4;
  const int r0  = ty * 4, c0 = tx * 4;
  const int ar  = t >> 2, ak  = (t & 3) * 8;
  const int bk  = t >> 3, bn8 = (t & 7) * 8;

  float acc[4][4] = {};
  for (int kt = 0; kt < 1024; kt += 32) {
    float tmp[8];
    load8_f32(X + (size_t)(gm0 + ar) * 1024 + kt + ak, tmp);
#pragma unroll
    for (int i = 0; i < 8; i++) As[ar][ak + i] = tmp[i];
    load8_f32(W + (size_t)(kt + bk) * 3072 + gn0 + bn8, tmp);
#pragma unroll
    for (int i = 0; i < 8; i++) Bs[bk][bn8 + i] = tmp[i];
    __syncthreads();
#pragma unroll
    for (int kk = 0; kk < 32; kk++) {
      float a[4];
      a[0] = As[r0 + 0][kk]; a[1] = As[r0 + 1][kk];
      a[2] = As[r0 + 2][kk]; a[3] = As[r0 + 3][kk];
      float4 bq = *reinterpret_cast<const float4*>(&Bs[kk][c0]);
      float bv[4] = {bq.x, bq.y, bq.z, bq.w};
#pragma unroll
      for (int i = 0; i < 4; i++)
#pragma unroll
        for (int j = 0; j < 4; j++) acc[i][j] += a[i] * bv[j];
    }
    __syncthreads();
  }
#pragma unroll
  for (int j = 0; j < 4; j++) {
    const int gc = gn0 + c0 + j;                   // 0..3071
    const float bvs = bias[gc];
    const int which = gc >> 10;                    // 0=Q 1=K 2=V
    const int cc = gc & 1023;
    const int hh = cc >> 6, d = cc & 63;
#pragma unroll
    for (int i = 0; i < 4; i++) {
      const int gr = gm0 + r0 + i;
      const int bb = gr >> 11, s = gr & 2047;
      const float val = acc[i][j] + bvs;
      if (which == 0)
        q[(((size_t)(bb * 16 + hh) * 2048 + s) * 64 + d)] = __float2bfloat16(val);
      else if (which == 1)
        k[(((size_t)(bb * 16 + hh) * 2048 + s) * 64 + d)] = __float2bfloat16(val);
      else
        v[(((size_t)(bb * 16 + hh) * 64 + d) * 2048 + s)] = __float2bfloat16(val);
    }
  }
}

// ---------- Kernel 2: causal flash attention via MFMA ----------
// 4 waves/block, 64 q-rows/block (16/wave), KVBLK=64, one head per block.z/y.
// Q,K bf16 BHSD; V bf16 BHDS. O overwrites this block's OWN Q slab
// (Q consumed into registers at kernel start; O written at the very end).
// LDS rows padded to 72 elements (144B = 9x16B slots): 9*row mod 8 is a
// bijection -> all ds_read_b128 fragment reads and staging writes are
// 2-way-or-free on the 32 banks (2-way is free per CDNA4).
__global__ __launch_bounds__(256)
void attn_f(bf16* __restrict__ qo, const bf16* __restrict__ k, const bf16* __restrict__ v)
{
  __shared__ __align__(16) bf16 Ks[64][72];       // K tile, row = k, col = d
  __shared__ __align__(16) bf16 Vt[64][72];       // V tile, row = d, col = k
  __shared__ __align__(16) bf16 Ps[4][16][72];    // per-wave P tile, row = q, col = k

  const int t    = threadIdx.x;
  const int qt   = (int)(gridDim.x - 1 - blockIdx.x);  // longest blocks first
  const int h    = blockIdx.y, b = blockIdx.z;
  const size_t basebh = (size_t)(b * 16 + h) * 2048 * 64;  // also == V head base

  const int w    = t >> 6;        // wave 0..3
  const int lane = t & 63;
  const int g    = lane >> 4;     // 0..3
  const int l15  = lane & 15;
  const int qb   = qt * 64 + w * 16;

  // Q A-fragments: lane holds Q[qb+l15][c*32 + g*8 .. +8]  (A: row=l%16, k=(l/16)*8+i)
  const bf16* qrow = qo + basebh + (size_t)(qb + l15) * 64;
  bf16x8 qf0 = *reinterpret_cast<const bf16x8*>(qrow + g * 8);
  bf16x8 qf1 = *reinterpret_cast<const bf16x8*>(qrow + 32 + g * 8);

  f32x4 acc[4] = {{0,0,0,0},{0,0,0,0},{0,0,0,0},{0,0,0,0}};
  float m_run[4] = {NEG_BIG, NEG_BIG, NEG_BIG, NEG_BIG};
  float l_run[4] = {0.f, 0.f, 0.f, 0.f};

  const int sr = t >> 3;          // staging row 0..31
  const int sc = (t & 7) * 8;     // staging col (elements)

  for (int ct = 0; ct <= qt; ++ct) {
    const int kv0 = ct * 64;
    __syncthreads();              // all waves done reading previous tile
#pragma unroll
    for (int p = 0; p < 2; ++p) {
      const int row = p * 32 + sr;
      *reinterpret_cast<uint4*>(&Ks[row][sc]) =
          *reinterpret_cast<const uint4*>(k + basebh + (size_t)(kv0 + row) * 64 + sc);
      *reinterpret_cast<uint4*>(&Vt[row][sc]) =
          *reinterpret_cast<const uint4*>(v + basebh + (size_t)row * 2048 + kv0 + sc);
    }
    __syncthreads();

    // ---- S = Q K^T * scale  (C layout: row q = g*4+reg, col k = l15) ----
    f32x4 st[4];
#pragma unroll
    for (int kt = 0; kt < 4; ++kt) {
      const int kr = kt * 16 + l15;
      bf16x8 kf0 = *reinterpret_cast<const bf16x8*>(&Ks[kr][g * 8]);
      bf16x8 kf1 = *reinterpret_cast<const bf16x8*>(&Ks[kr][32 + g * 8]);
      f32x4 c4 = {0,0,0,0};
      c4 = __builtin_amdgcn_mfma_f32_16x16x32_bf16(qf0, kf0, c4, 0, 0, 0);
      c4 = __builtin_amdgcn_mfma_f32_16x16x32_bf16(qf1, kf1, c4, 0, 0, 0);
      st[kt] = c4 * 0.125f;
    }
    if (ct == qt) {               // causal mask, diagonal tile only
#pragma unroll
      for (int kt = 0; kt < 4; ++kt) {
        const int kg = kv0 + kt * 16 + l15;
#pragma unroll
        for (int r = 0; r < 4; ++r)
          if (kg > qb + g * 4 + r) st[kt][r] = NEG_BIG;
      }
    }

    // ---- online softmax (row reduce across the 16 lanes sharing g) ----
    float alpha[4];
#pragma unroll
    for (int r = 0; r < 4; ++r) {
      float m = fmaxf(fmaxf(st[0][r], st[1][r]), fmaxf(st[2][r], st[3][r]));
#pragma unroll
      for (int msk = 1; msk < 16; msk <<= 1) m = fmaxf(m, __shfl_xor(m, msk, 16));
      const float mn = fmaxf(m_run[r], m);
      alpha[r] = __expf(m_run[r] - mn);
      float ps = 0.f;
#pragma unroll
      for (int kt = 0; kt < 4; ++kt) {
        const float pv = __expf(st[kt][r] - mn);
        st[kt][r] = pv;
        ps += pv;
      }
#pragma unroll
      for (int msk = 1; msk < 16; msk <<= 1) ps += __shfl_xor(ps, msk, 16);
      l_run[r] = l_run[r] * alpha[r] + ps;
      m_run[r] = mn;
    }
#pragma unroll
    for (int dt = 0; dt < 4; ++dt)
#pragma unroll
      for (int r = 0; r < 4; ++r) acc[dt][r] *= alpha[r];

    // ---- P (bf16) -> per-wave LDS; same-wave LDS ops are in-order ----
#pragma unroll
    for (int kt = 0; kt < 4; ++kt)
#pragma unroll
      for (int r = 0; r < 4; ++r)
        Ps[w][g * 4 + r][kt * 16 + l15] = __float2bfloat16(st[kt][r]);
    __builtin_amdgcn_sched_barrier(0);

    // ---- O += P V  (A = P from Ps, B = V from Vt; both contiguous 16B) ----
#pragma unroll
    for (int kc = 0; kc < 2; ++kc) {
      bf16x8 pf = *reinterpret_cast<const bf16x8*>(&Ps[w][l15][kc * 32 + g * 8]);
#pragma unroll
      for (int dt = 0; dt < 4; ++dt) {
        bf16x8 vf = *reinterpret_cast<const bf16x8*>(&Vt[dt * 16 + l15][kc * 32 + g * 8]);
        acc[dt] = __builtin_amdgcn_mfma_f32_16x16x32_bf16(pf, vf, acc[dt], 0, 0, 0);
      }
    }
  }

  // ---- epilogue: O = acc / l, in-place over this block's Q slab ----
  float inv[4];
#pragma unroll
  for (int r = 0; r < 4; ++r) inv[r] = 1.f / l_run[r];
  bf16* op = qo + basebh;
#pragma unroll
  for (int dt = 0; dt < 4; ++dt)
#pragma unroll
    for (int r = 0; r < 4; ++r)
      op[(size_t)(qb + g * 4 + r) * 64 + dt * 16 + l15] =
          __float2bfloat16(acc[dt][r] * inv[r]);
}

// ---------- Kernel 3: projection. A = O bf16 BHSD (ws). ----------
__global__ __launch_bounds__(256)
void proj_f(const bf16* __restrict__ A, const float* __restrict__ W,
            const float* __restrict__ bias, float* __restrict__ out)
{
  __shared__ float As[64][33];
  __shared__ float Bs[32][68];
  const int t   = threadIdx.x;
  const int bm  = blockIdx.y, bn = blockIdx.x;
  const int gm0 = bm * 64, gn0 = bn * 64;
  const int tx  = t & 15, ty = t >> 4;
  const int r0  = ty * 4, c0 = tx * 4;
  const int ar  = t >> 2, ak  = (t & 3) * 8;
  const int bk  = t >> 3, bn8 = (t & 7) * 8;

  const int gr_l = gm0 + ar;
  const int bb_l = gr_l >> 11, s_l = gr_l & 2047;

  float acc[4][4] = {};
  for (int kt = 0; kt < 1024; kt += 32) {
    float tmp[8];
    const int c = kt + ak;
    const int hh = c >> 6, dd = c & 63;
    load8_bf(A + ((size_t)bb_l * 2097152 + (size_t)hh * 131072 + (size_t)s_l * 64 + dd), tmp);
#pragma unroll
    for (int i = 0; i < 8; i++) As[ar][ak + i] = tmp[i];
    load8_f32(W + (size_t)(kt + bk) * 1024 + gn0 + bn8, tmp);
#pragma unroll
    for (int i = 0; i < 8; i++) Bs[bk][bn8 + i] = tmp[i];
    __syncthreads();
#pragma unroll
    for (int kk = 0; kk < 32; kk++) {
      float a[4];
      a[0] = As[r0 + 0][kk]; a[1] = As[r0 + 1][kk];
      a[2] = As[r0 + 2][kk]; a[3] = As[r0 + 3][kk];
      float4 bq = *reinterpret_cast<const float4*>(&Bs[kk][c0]);
      float bv[4] = {bq.x, bq.y, bq.z, bq.w};
#pragma unroll
      for (int i = 0; i < 4; i++)
#pragma unroll
        for (int j = 0; j < 4; j++) acc[i][j] += a[i] * bv[j];
    }
    __syncthreads();
  }
#pragma unroll
  for (int i = 0; i < 4; i++) {
    const int gr = gm0 + r0 + i;
    float4 o4 = make_float4(acc[i][0] + bias[gn0 + c0 + 0],
                            acc[i][1] + bias[gn0 + c0 + 1],
                            acc[i][2] + bias[gn0 + c0 + 2],
                            acc[i][3] + bias[gn0 + c0 + 3]);
    *reinterpret_cast<float4*>(out + (size_t)gr * 1024 + gn0 + c0) = o4;
  }
}

extern "C" void kernel_launch(void* const* d_in, const int* in_sizes, int n_in,
                              void* d_out, int out_size, void* d_ws, size_t ws_size,
                              hipStream_t stream)
{
  const float *x = nullptr, *W_attn = nullptr, *b_attn = nullptr,
              *W_proj = nullptr, *b_proj = nullptr;
  for (int i = 0; i < n_in; i++) {
    switch (in_sizes[i]) {
      case 8388608: x      = (const float*)d_in[i]; break;  // [4,2048,1024]
      case 3145728: W_attn = (const float*)d_in[i]; break;  // [1024,3072]
      case 3072:    b_attn = (const float*)d_in[i]; break;
      case 1048576: W_proj = (const float*)d_in[i]; break;  // [1024,1024]
      case 1024:    b_proj = (const float*)d_in[i]; break;
      default: break;
    }
  }
  if (!x || !W_attn || !b_attn || !W_proj || !b_proj) {
    x = (const float*)d_in[0]; W_attn = (const float*)d_in[1];
    b_attn = (const float*)d_in[2]; W_proj = (const float*)d_in[3];
    b_proj = (const float*)d_in[4];
  }
  float* out = (float*)d_out;        // 8388608 f32 = 32 MiB

  // Memory plan (inputs never written; ws requirement 16 MiB):
  //   Q -> ws[0:16M)  bf16 BHSD      (later overwritten block-privately by O)
  //   K -> d_out bytes [0:16M)  bf16 BHSD   } dead before proj's f32 writes
  //   V -> d_out bytes [16M:32M) bf16 BHDS  }  (transposed for MFMA PV)
  const size_t NE = 8388608;         // bf16 elements per 16 MiB tensor
  bf16* qb = (bf16*)d_ws;
  bf16* kb = (bf16*)d_out;
  bf16* vb = kb + NE;

  qkv_f <<<dim3(48, 128), 256, 0, stream>>>(x, W_attn, b_attn, qb, kb, vb);
  attn_f<<<dim3(32, 16, 4), 256, 0, stream>>>(qb, kb, vb);
  proj_f<<<dim3(16, 128), 256, 0, stream>>>(qb, W_proj, b_proj, out);
}

// Round 2
// 394.577 us; speedup vs baseline: 6.0271x; 2.9020x over previous
//
#include <hip/hip_runtime.h>
#include <hip/hip_bf16.h>

typedef __hip_bfloat16 bf16;
#define NEG_BIG (-3.0e38f)

// MFMA fragment types (gfx950: v_mfma_f32_16x16x32_bf16 takes <8 x bfloat>)
typedef __bf16 bf16x8 __attribute__((ext_vector_type(8)));
typedef float  f32x4  __attribute__((ext_vector_type(4)));

__device__ inline void load8_f32(const float* p, float* o) {
  float4 a = *reinterpret_cast<const float4*>(p);
  float4 b = *reinterpret_cast<const float4*>(p + 4);
  o[0]=a.x; o[1]=a.y; o[2]=a.z; o[3]=a.w;
  o[4]=b.x; o[5]=b.y; o[6]=b.z; o[7]=b.w;
}

// k-granule XOR swizzle: breaks the 8-way bank conflict of n-row b128 writes
// at row-stride 80B. Element offset of 8-elem granule kg within a row.
__device__ inline int swz8(int row, int kg) { return ((kg ^ ((row >> 3) & 3)) << 3); }

// ---------- Kernel 1: QKV GEMM via MFMA ----------
// X[8192,1024]f32 @ W[1024,3072]f32 + b.  128x128 tile, 4 waves 2x2 (64x64/wave).
// A,B staged to LDS as bf16 (cvt in regs). B stored transposed Bs[n][k] so the
// B-operand fragment (8 consecutive k per output col) is one ds_read_b128.
// Q -> ws bf16 BHSD; K -> d_out[0:16M) bf16 BHSD; V -> d_out[16M:32M) bf16 BHDS.
__global__ __launch_bounds__(256)
void qkv_f(const float* __restrict__ X, const float* __restrict__ W,
           const float* __restrict__ bias,
           bf16* __restrict__ q, bf16* __restrict__ k, bf16* __restrict__ v)
{
  __shared__ __align__(16) bf16 As[128][40];   // row = m, 32 k + pad
  __shared__ __align__(16) bf16 Bs[128][40];   // row = n, 32 k + pad
  const int t   = threadIdx.x;
  const int bn  = blockIdx.x, bm = blockIdx.y;   // (24, 64)
  const int gm0 = bm * 128, gn0 = bn * 128;
  const int w    = t >> 6, lane = t & 63;
  const int g    = lane >> 4, l15 = lane & 15;
  const int wr   = w >> 1, wc = w & 1;

  const int am  = t >> 1, akg = (t & 1) * 2;   // A staging: row am, granules akg,akg+1
  const int bn0 = t & 63;                       // B staging: rows bn0,bn0+64, granule w

  f32x4 acc[4][4];
#pragma unroll
  for (int i = 0; i < 4; i++)
#pragma unroll
    for (int j = 0; j < 4; j++) acc[i][j] = {0.f, 0.f, 0.f, 0.f};

  for (int kt = 0; kt < 1024; kt += 32) {
    float a32[16];
    load8_f32(X + (size_t)(gm0 + am) * 1024 + kt + akg * 8, a32);
    load8_f32(X + (size_t)(gm0 + am) * 1024 + kt + akg * 8 + 8, a32 + 8);
    float wb0[8], wb1[8];
#pragma unroll
    for (int kk = 0; kk < 8; kk++) {
      const float* wp = W + (size_t)(kt + w * 8 + kk) * 3072 + gn0 + bn0;
      wb0[kk] = wp[0]; wb1[kk] = wp[64];
    }
    __align__(16) bf16 ab[16], bb0[8], bb1[8];
#pragma unroll
    for (int i = 0; i < 16; i++) ab[i] = __float2bfloat16(a32[i]);
#pragma unroll
    for (int i = 0; i < 8; i++) { bb0[i] = __float2bfloat16(wb0[i]); bb1[i] = __float2bfloat16(wb1[i]); }
    __syncthreads();   // previous iteration's fragment reads done
    *reinterpret_cast<uint4*>(&As[am][swz8(am, akg)])           = reinterpret_cast<const uint4*>(ab)[0];
    *reinterpret_cast<uint4*>(&As[am][swz8(am, akg + 1)])       = reinterpret_cast<const uint4*>(ab)[1];
    *reinterpret_cast<uint4*>(&Bs[bn0][swz8(bn0, w)])           = *reinterpret_cast<const uint4*>(bb0);
    *reinterpret_cast<uint4*>(&Bs[bn0 + 64][swz8(bn0 + 64, w)]) = *reinterpret_cast<const uint4*>(bb1);
    __syncthreads();

    bf16x8 af[4], bfr[4];
#pragma unroll
    for (int mt = 0; mt < 4; mt++) {
      const int r_ = wr * 64 + mt * 16 + l15;
      af[mt] = *reinterpret_cast<const bf16x8*>(&As[r_][swz8(r_, g)]);
    }
#pragma unroll
    for (int nt = 0; nt < 4; nt++) {
      const int r_ = wc * 64 + nt * 16 + l15;
      bfr[nt] = *reinterpret_cast<const bf16x8*>(&Bs[r_][swz8(r_, g)]);
    }
#pragma unroll
    for (int mt = 0; mt < 4; mt++)
#pragma unroll
      for (int nt = 0; nt < 4; nt++)
        acc[mt][nt] = __builtin_amdgcn_mfma_f32_16x16x32_bf16(af[mt], bfr[nt], acc[mt][nt], 0, 0, 0);
  }

  // Epilogue: C layout row = g*4+r, col = l15. Scatter to Q/K/V (V transposed).
#pragma unroll
  for (int nt = 0; nt < 4; nt++) {
    const int gc  = gn0 + wc * 64 + nt * 16 + l15;   // never crosses Q/K/V or head boundary
    const float bvs = bias[gc];
    const int which = gc >> 10;
    const int cc = gc & 1023;
    const int hh = cc >> 6, d = cc & 63;
    bf16* dst = (which == 0) ? q : ((which == 1) ? k : v);
#pragma unroll
    for (int mt = 0; mt < 4; mt++)
#pragma unroll
      for (int r = 0; r < 4; r++) {
        const int gr = gm0 + wr * 64 + mt * 16 + g * 4 + r;
        const int bb = gr >> 11, s = gr & 2047;
        const float val = acc[mt][nt][r] + bvs;
        if (which == 2)
          dst[((size_t)(bb * 16 + hh) * 64 + d) * 2048 + s] = __float2bfloat16(val);
        else
          dst[((size_t)(bb * 16 + hh) * 2048 + s) * 64 + d] = __float2bfloat16(val);
      }
  }
}

// ---------- Kernel 2: causal flash attention via MFMA (unchanged) ----------
__global__ __launch_bounds__(256)
void attn_f(bf16* __restrict__ qo, const bf16* __restrict__ k, const bf16* __restrict__ v)
{
  __shared__ __align__(16) bf16 Ks[32 * 144];     // K tile as [64][72]
  __shared__ __align__(16) bf16 Vt[32 * 144];     // V tile as [64][72] (row = d)
  __shared__ __align__(16) bf16 Ps[4][16][72];    // per-wave P tile

  bf16 (*Ksr)[72] = reinterpret_cast<bf16 (*)[72]>(Ks);
  bf16 (*Vtr)[72] = reinterpret_cast<bf16 (*)[72]>(Vt);

  const int t    = threadIdx.x;
  const int qt   = (int)(gridDim.x - 1 - blockIdx.x);
  const int h    = blockIdx.y, b = blockIdx.z;
  const size_t basebh = (size_t)(b * 16 + h) * 2048 * 64;

  const int w    = t >> 6;
  const int lane = t & 63;
  const int g    = lane >> 4;
  const int l15  = lane & 15;
  const int qb   = qt * 64 + w * 16;

  const bf16* qrow = qo + basebh + (size_t)(qb + l15) * 64;
  bf16x8 qf0 = *reinterpret_cast<const bf16x8*>(qrow + g * 8);
  bf16x8 qf1 = *reinterpret_cast<const bf16x8*>(qrow + 32 + g * 8);

  f32x4 acc[4] = {{0,0,0,0},{0,0,0,0},{0,0,0,0},{0,0,0,0}};
  float m_run[4] = {NEG_BIG, NEG_BIG, NEG_BIG, NEG_BIG};
  float l_run[4] = {0.f, 0.f, 0.f, 0.f};

  const int sr = t >> 3;
  const int sc = (t & 7) * 8;

  for (int ct = 0; ct <= qt; ++ct) {
    const int kv0 = ct * 64;
    __syncthreads();
#pragma unroll
    for (int p = 0; p < 2; ++p) {
      const int row = p * 32 + sr;
      *reinterpret_cast<uint4*>(&Ksr[row][sc]) =
          *reinterpret_cast<const uint4*>(k + basebh + (size_t)(kv0 + row) * 64 + sc);
      *reinterpret_cast<uint4*>(&Vtr[row][sc]) =
          *reinterpret_cast<const uint4*>(v + basebh + (size_t)row * 2048 + kv0 + sc);
    }
    __syncthreads();

    f32x4 st[4];
#pragma unroll
    for (int kt = 0; kt < 4; ++kt) {
      const int kr = kt * 16 + l15;
      bf16x8 kf0 = *reinterpret_cast<const bf16x8*>(&Ksr[kr][g * 8]);
      bf16x8 kf1 = *reinterpret_cast<const bf16x8*>(&Ksr[kr][32 + g * 8]);
      f32x4 c4 = {0,0,0,0};
      c4 = __builtin_amdgcn_mfma_f32_16x16x32_bf16(qf0, kf0, c4, 0, 0, 0);
      c4 = __builtin_amdgcn_mfma_f32_16x16x32_bf16(qf1, kf1, c4, 0, 0, 0);
      st[kt] = c4 * 0.125f;
    }
    if (ct == qt) {
#pragma unroll
      for (int kt = 0; kt < 4; ++kt) {
        const int kg = kv0 + kt * 16 + l15;
#pragma unroll
        for (int r = 0; r < 4; ++r)
          if (kg > qb + g * 4 + r) st[kt][r] = NEG_BIG;
      }
    }

    float alpha[4];
#pragma unroll
    for (int r = 0; r < 4; ++r) {
      float m = fmaxf(fmaxf(st[0][r], st[1][r]), fmaxf(st[2][r], st[3][r]));
#pragma unroll
      for (int msk = 1; msk < 16; msk <<= 1) m = fmaxf(m, __shfl_xor(m, msk, 16));
      const float mn = fmaxf(m_run[r], m);
      alpha[r] = __expf(m_run[r] - mn);
      float ps = 0.f;
#pragma unroll
      for (int kt = 0; kt < 4; ++kt) {
        const float pv = __expf(st[kt][r] - mn);
        st[kt][r] = pv;
        ps += pv;
      }
#pragma unroll
      for (int msk = 1; msk < 16; msk <<= 1) ps += __shfl_xor(ps, msk, 16);
      l_run[r] = l_run[r] * alpha[r] + ps;
      m_run[r] = mn;
    }
#pragma unroll
    for (int dt = 0; dt < 4; ++dt)
#pragma unroll
      for (int r = 0; r < 4; ++r) acc[dt][r] *= alpha[r];

#pragma unroll
    for (int kt = 0; kt < 4; ++kt)
#pragma unroll
      for (int r = 0; r < 4; ++r)
        Ps[w][g * 4 + r][kt * 16 + l15] = __float2bfloat16(st[kt][r]);
    __builtin_amdgcn_sched_barrier(0);

#pragma unroll
    for (int kc = 0; kc < 2; ++kc) {
      bf16x8 pf = *reinterpret_cast<const bf16x8*>(&Ps[w][l15][kc * 32 + g * 8]);
#pragma unroll
      for (int dt = 0; dt < 4; ++dt) {
        bf16x8 vf = *reinterpret_cast<const bf16x8*>(&Vtr[dt * 16 + l15][kc * 32 + g * 8]);
        acc[dt] = __builtin_amdgcn_mfma_f32_16x16x32_bf16(pf, vf, acc[dt], 0, 0, 0);
      }
    }
  }

  float inv[4];
#pragma unroll
  for (int r = 0; r < 4; ++r) inv[r] = 1.f / l_run[r];
  bf16* op = qo + basebh;
#pragma unroll
  for (int dt = 0; dt < 4; ++dt)
#pragma unroll
    for (int r = 0; r < 4; ++r)
      op[(size_t)(qb + g * 4 + r) * 64 + dt * 16 + l15] =
          __float2bfloat16(acc[dt][r] * inv[r]);
}

// ---------- Kernel 3: projection via MFMA ----------
// A = O bf16 BHSD (ws), already bf16 -> raw b128 staging (no cvt).
// W_proj f32 -> bf16 staged transposed, out f32 [8192,1024].
__global__ __launch_bounds__(256)
void proj_f(const bf16* __restrict__ A, const float* __restrict__ W,
            const float* __restrict__ bias, float* __restrict__ out)
{
  __shared__ __align__(16) bf16 As[128][40];
  __shared__ __align__(16) bf16 Bs[128][40];
  const int t   = threadIdx.x;
  const int bn  = blockIdx.x, bm = blockIdx.y;   // (8, 64)
  const int gm0 = bm * 128, gn0 = bn * 128;
  const int w    = t >> 6, lane = t & 63;
  const int g    = lane >> 4, l15 = lane & 15;
  const int wr   = w >> 1, wc = w & 1;

  const int am  = t >> 1, akg = (t & 1) * 2;
  const int bn0 = t & 63;

  const int gr_l = gm0 + am;
  const int bb_l = gr_l >> 11, s_l = gr_l & 2047;

  f32x4 acc[4][4];
#pragma unroll
  for (int i = 0; i < 4; i++)
#pragma unroll
    for (int j = 0; j < 4; j++) acc[i][j] = {0.f, 0.f, 0.f, 0.f};

  for (int kt = 0; kt < 1024; kt += 32) {
    const int c0 = kt + akg * 8;            // 16-aligned: stays within one head's 64 cols
    const int hh = c0 >> 6, dd = c0 & 63;
    const uint4* ap = reinterpret_cast<const uint4*>(
        A + ((size_t)bb_l * 2097152 + (size_t)hh * 131072 + (size_t)s_l * 64 + dd));
    uint4 a0 = ap[0], a1 = ap[1];
    float wb0[8], wb1[8];
#pragma unroll
    for (int kk = 0; kk < 8; kk++) {
      const float* wp = W + (size_t)(kt + w * 8 + kk) * 1024 + gn0 + bn0;
      wb0[kk] = wp[0]; wb1[kk] = wp[64];
    }
    __align__(16) bf16 bb0[8], bb1[8];
#pragma unroll
    for (int i = 0; i < 8; i++) { bb0[i] = __float2bfloat16(wb0[i]); bb1[i] = __float2bfloat16(wb1[i]); }
    __syncthreads();
    *reinterpret_cast<uint4*>(&As[am][swz8(am, akg)])           = a0;
    *reinterpret_cast<uint4*>(&As[am][swz8(am, akg + 1)])       = a1;
    *reinterpret_cast<uint4*>(&Bs[bn0][swz8(bn0, w)])           = *reinterpret_cast<const uint4*>(bb0);
    *reinterpret_cast<uint4*>(&Bs[bn0 + 64][swz8(bn0 + 64, w)]) = *reinterpret_cast<const uint4*>(bb1);
    __syncthreads();

    bf16x8 af[4], bfr[4];
#pragma unroll
    for (int mt = 0; mt < 4; mt++) {
      const int r_ = wr * 64 + mt * 16 + l15;
      af[mt] = *reinterpret_cast<const bf16x8*>(&As[r_][swz8(r_, g)]);
    }
#pragma unroll
    for (int nt = 0; nt < 4; nt++) {
      const int r_ = wc * 64 + nt * 16 + l15;
      bfr[nt] = *reinterpret_cast<const bf16x8*>(&Bs[r_][swz8(r_, g)]);
    }
#pragma unroll
    for (int mt = 0; mt < 4; mt++)
#pragma unroll
      for (int nt = 0; nt < 4; nt++)
        acc[mt][nt] = __builtin_amdgcn_mfma_f32_16x16x32_bf16(af[mt], bfr[nt], acc[mt][nt], 0, 0, 0);
  }

#pragma unroll
  for (int nt = 0; nt < 4; nt++) {
    const int gc = gn0 + wc * 64 + nt * 16 + l15;
    const float bvs = bias[gc];
#pragma unroll
    for (int mt = 0; mt < 4; mt++)
#pragma unroll
      for (int r = 0; r < 4; r++) {
        const int gr = gm0 + wr * 64 + mt * 16 + g * 4 + r;
        out[(size_t)gr * 1024 + gc] = acc[mt][nt][r] + bvs;
      }
  }
}

extern "C" void kernel_launch(void* const* d_in, const int* in_sizes, int n_in,
                              void* d_out, int out_size, void* d_ws, size_t ws_size,
                              hipStream_t stream)
{
  const float *x = nullptr, *W_attn = nullptr, *b_attn = nullptr,
              *W_proj = nullptr, *b_proj = nullptr;
  for (int i = 0; i < n_in; i++) {
    switch (in_sizes[i]) {
      case 8388608: x      = (const float*)d_in[i]; break;  // [4,2048,1024]
      case 3145728: W_attn = (const float*)d_in[i]; break;  // [1024,3072]
      case 3072:    b_attn = (const float*)d_in[i]; break;
      case 1048576: W_proj = (const float*)d_in[i]; break;  // [1024,1024]
      case 1024:    b_proj = (const float*)d_in[i]; break;
      default: break;
    }
  }
  if (!x || !W_attn || !b_attn || !W_proj || !b_proj) {
    x = (const float*)d_in[0]; W_attn = (const float*)d_in[1];
    b_attn = (const float*)d_in[2]; W_proj = (const float*)d_in[3];
    b_proj = (const float*)d_in[4];
  }
  float* out = (float*)d_out;        // 8388608 f32 = 32 MiB

  // Memory plan (inputs never written; ws requirement 16 MiB):
  //   Q -> ws[0:16M)  bf16 BHSD      (later overwritten block-privately by O)
  //   K -> d_out bytes [0:16M)  bf16 BHSD   } dead before proj's f32 writes
  //   V -> d_out bytes [16M:32M) bf16 BHDS  }  (transposed for MFMA PV)
  const size_t NE = 8388608;         // bf16 elements per 16 MiB tensor
  bf16* qb = (bf16*)d_ws;
  bf16* kb = (bf16*)d_out;
  bf16* vb = kb + NE;

  qkv_f <<<dim3(24, 64), 256, 0, stream>>>(x, W_attn, b_attn, qb, kb, vb);
  attn_f<<<dim3(32, 16, 4), 256, 0, stream>>>(qb, kb, vb);
  proj_f<<<dim3(8, 64), 256, 0, stream>>>(qb, W_proj, b_proj, out);
}

// Round 3
// 301.669 us; speedup vs baseline: 7.8833x; 1.3080x over previous
//
#include <hip/hip_runtime.h>
#include <hip/hip_bf16.h>

typedef __hip_bfloat16 bf16;
#define NEG_BIG (-3.0e38f)

// MFMA fragment types (gfx950: v_mfma_f32_16x16x32_bf16 takes <8 x bfloat>)
typedef __bf16 bf16x8 __attribute__((ext_vector_type(8)));
typedef float  f32x4  __attribute__((ext_vector_type(4)));

__device__ inline void load8_f32(const float* p, float* o) {
  float4 a = *reinterpret_cast<const float4*>(p);
  float4 b = *reinterpret_cast<const float4*>(p + 4);
  o[0]=a.x; o[1]=a.y; o[2]=a.z; o[3]=a.w;
  o[4]=b.x; o[5]=b.y; o[6]=b.z; o[7]=b.w;
}

// k-granule XOR swizzle: breaks the 8-way bank conflict of n-row b128 writes
// at row-stride 80B. Element offset of 8-elem granule kg within a row.
__device__ inline int swz8(int row, int kg) { return ((kg ^ ((row >> 3) & 3)) << 3); }

// ---------- Kernel 1: QKV GEMM via MFMA ----------
// X[8192,1024]f32 @ W[1024,3072]f32 + b.  128x128 tile, 4 waves 2x2 (64x64/wave).
// Q is stored PRE-SCALED by 1/sqrt(HEAD_DIM)=0.125 (folded out of attention).
// Q -> ws bf16 BHSD; K -> d_out[0:16M) bf16 BHSD; V -> d_out[16M:32M) bf16 BHDS.
__global__ __launch_bounds__(256)
void qkv_f(const float* __restrict__ X, const float* __restrict__ W,
           const float* __restrict__ bias,
           bf16* __restrict__ q, bf16* __restrict__ k, bf16* __restrict__ v)
{
  __shared__ __align__(16) bf16 As[128][40];   // row = m, 32 k + pad
  __shared__ __align__(16) bf16 Bs[128][40];   // row = n, 32 k + pad
  const int t   = threadIdx.x;
  const int bn  = blockIdx.x, bm = blockIdx.y;   // (24, 64)
  const int gm0 = bm * 128, gn0 = bn * 128;
  const int w    = t >> 6, lane = t & 63;
  const int g    = lane >> 4, l15 = lane & 15;
  const int wr   = w >> 1, wc = w & 1;

  const int am  = t >> 1, akg = (t & 1) * 2;   // A staging: row am, granules akg,akg+1
  const int bn0 = t & 63;                       // B staging: rows bn0,bn0+64, granule w

  f32x4 acc[4][4];
#pragma unroll
  for (int i = 0; i < 4; i++)
#pragma unroll
    for (int j = 0; j < 4; j++) acc[i][j] = {0.f, 0.f, 0.f, 0.f};

  for (int kt = 0; kt < 1024; kt += 32) {
    float a32[16];
    load8_f32(X + (size_t)(gm0 + am) * 1024 + kt + akg * 8, a32);
    load8_f32(X + (size_t)(gm0 + am) * 1024 + kt + akg * 8 + 8, a32 + 8);
    float wb0[8], wb1[8];
#pragma unroll
    for (int kk = 0; kk < 8; kk++) {
      const float* wp = W + (size_t)(kt + w * 8 + kk) * 3072 + gn0 + bn0;
      wb0[kk] = wp[0]; wb1[kk] = wp[64];
    }
    __align__(16) bf16 ab[16], bb0[8], bb1[8];
#pragma unroll
    for (int i = 0; i < 16; i++) ab[i] = __float2bfloat16(a32[i]);
#pragma unroll
    for (int i = 0; i < 8; i++) { bb0[i] = __float2bfloat16(wb0[i]); bb1[i] = __float2bfloat16(wb1[i]); }
    __syncthreads();   // previous iteration's fragment reads done
    *reinterpret_cast<uint4*>(&As[am][swz8(am, akg)])           = reinterpret_cast<const uint4*>(ab)[0];
    *reinterpret_cast<uint4*>(&As[am][swz8(am, akg + 1)])       = reinterpret_cast<const uint4*>(ab)[1];
    *reinterpret_cast<uint4*>(&Bs[bn0][swz8(bn0, w)])           = *reinterpret_cast<const uint4*>(bb0);
    *reinterpret_cast<uint4*>(&Bs[bn0 + 64][swz8(bn0 + 64, w)]) = *reinterpret_cast<const uint4*>(bb1);
    __syncthreads();

    bf16x8 af[4], bfr[4];
#pragma unroll
    for (int mt = 0; mt < 4; mt++) {
      const int r_ = wr * 64 + mt * 16 + l15;
      af[mt] = *reinterpret_cast<const bf16x8*>(&As[r_][swz8(r_, g)]);
    }
#pragma unroll
    for (int nt = 0; nt < 4; nt++) {
      const int r_ = wc * 64 + nt * 16 + l15;
      bfr[nt] = *reinterpret_cast<const bf16x8*>(&Bs[r_][swz8(r_, g)]);
    }
#pragma unroll
    for (int mt = 0; mt < 4; mt++)
#pragma unroll
      for (int nt = 0; nt < 4; nt++)
        acc[mt][nt] = __builtin_amdgcn_mfma_f32_16x16x32_bf16(af[mt], bfr[nt], acc[mt][nt], 0, 0, 0);
  }

  // Epilogue: C layout row = g*4+r, col = l15. Scatter to Q/K/V (V transposed).
#pragma unroll
  for (int nt = 0; nt < 4; nt++) {
    const int gc  = gn0 + wc * 64 + nt * 16 + l15;   // never crosses Q/K/V or head boundary
    const float bvs = bias[gc];
    const int which = gc >> 10;
    const int cc = gc & 1023;
    const int hh = cc >> 6, d = cc & 63;
    bf16* dst = (which == 0) ? q : ((which == 1) ? k : v);
#pragma unroll
    for (int mt = 0; mt < 4; mt++)
#pragma unroll
      for (int r = 0; r < 4; r++) {
        const int gr = gm0 + wr * 64 + mt * 16 + g * 4 + r;
        const int bb = gr >> 11, s = gr & 2047;
        float val = acc[mt][nt][r] + bvs;
        if (which == 0) val *= 0.125f;   // fold softmax scale into Q
        if (which == 2)
          dst[((size_t)(bb * 16 + hh) * 64 + d) * 2048 + s] = __float2bfloat16(val);
        else
          dst[((size_t)(bb * 16 + hh) * 2048 + s) * 64 + d] = __float2bfloat16(val);
      }
  }
}

// ---------- Kernel 2: causal flash attention via MFMA, swapped QK^T ----------
// 4 waves/block, 16 q-rows/wave, KVBLK=64. Q pre-scaled by 0.125.
// QK^T computed as mfma(K, Q): D row = k (g*4+r), col = q (l15) -> each lane
// holds all 16 P values of ONE q-row => in-lane softmax reduce + 2 shfl_xor.
// K/V staged async: next tile's global loads issued before current compute.
__global__ __launch_bounds__(256)
void attn_f(bf16* __restrict__ qo, const bf16* __restrict__ k, const bf16* __restrict__ v)
{
  __shared__ __align__(16) bf16 Ks[64][72];     // K tile, row = k, col = d
  __shared__ __align__(16) bf16 Vt[64][72];     // V tile, row = d, col = k
  __shared__ __align__(16) bf16 Ps[4][16][72];  // per-wave P, row = q, col = k

  const int t    = threadIdx.x;
  const int qt   = (int)(gridDim.x - 1 - blockIdx.x);  // longest blocks first
  const int h    = blockIdx.y, b = blockIdx.z;
  const size_t basebh = (size_t)(b * 16 + h) * 2048 * 64;

  const int w    = t >> 6;
  const int lane = t & 63;
  const int g    = lane >> 4;
  const int l15  = lane & 15;
  const int qb   = qt * 64 + w * 16;

  // Q B-fragments (same load as before; operand order in mfma is swapped)
  const bf16* qrow = qo + basebh + (size_t)(qb + l15) * 64;
  bf16x8 qf0 = *reinterpret_cast<const bf16x8*>(qrow + g * 8);
  bf16x8 qf1 = *reinterpret_cast<const bf16x8*>(qrow + 32 + g * 8);

  f32x4 acc[4] = {{0,0,0,0},{0,0,0,0},{0,0,0,0},{0,0,0,0}};
  float m_run = NEG_BIG, l_run = 0.f;   // canonical per-lane q = qb + l15

  const int sr = t >> 3;          // staging row 0..31
  const int sc = (t & 7) * 8;     // staging col (elements)
  const bf16* kbase = k + basebh;
  const bf16* vbase = v + basebh;

  uint4 kreg0, kreg1, vreg0, vreg1;
  {
    kreg0 = *reinterpret_cast<const uint4*>(kbase + (size_t)(sr) * 64 + sc);
    kreg1 = *reinterpret_cast<const uint4*>(kbase + (size_t)(32 + sr) * 64 + sc);
    vreg0 = *reinterpret_cast<const uint4*>(vbase + (size_t)sr * 2048 + sc);
    vreg1 = *reinterpret_cast<const uint4*>(vbase + (size_t)(32 + sr) * 2048 + sc);
  }

  for (int ct = 0; ct <= qt; ++ct) {
    const int kv0 = ct * 64;
    __syncthreads();              // all waves done reading previous tile
    *reinterpret_cast<uint4*>(&Ks[sr][sc])      = kreg0;
    *reinterpret_cast<uint4*>(&Ks[32 + sr][sc]) = kreg1;
    *reinterpret_cast<uint4*>(&Vt[sr][sc])      = vreg0;
    *reinterpret_cast<uint4*>(&Vt[32 + sr][sc]) = vreg1;
    if (ct < qt) {                // async prefetch of next tile (hides under compute)
      const int nv0 = kv0 + 64;
      kreg0 = *reinterpret_cast<const uint4*>(kbase + (size_t)(nv0 + sr) * 64 + sc);
      kreg1 = *reinterpret_cast<const uint4*>(kbase + (size_t)(nv0 + 32 + sr) * 64 + sc);
      vreg0 = *reinterpret_cast<const uint4*>(vbase + (size_t)sr * 2048 + nv0 + sc);
      vreg1 = *reinterpret_cast<const uint4*>(vbase + (size_t)(32 + sr) * 2048 + nv0 + sc);
    }
    __syncthreads();

    // ---- S^T tile: st[kt][r] = S[k = kv0+kt*16+g*4+r][q = qb+l15] ----
    f32x4 st[4];
#pragma unroll
    for (int kt = 0; kt < 4; ++kt) {
      const int kr = kt * 16 + l15;
      bf16x8 kf0 = *reinterpret_cast<const bf16x8*>(&Ks[kr][g * 8]);
      bf16x8 kf1 = *reinterpret_cast<const bf16x8*>(&Ks[kr][32 + g * 8]);
      f32x4 c4 = {0,0,0,0};
      c4 = __builtin_amdgcn_mfma_f32_16x16x32_bf16(kf0, qf0, c4, 0, 0, 0);
      c4 = __builtin_amdgcn_mfma_f32_16x16x32_bf16(kf1, qf1, c4, 0, 0, 0);
      st[kt] = c4;
    }
    if (ct == qt) {               // causal mask, diagonal tile only
      const int qg = qb + l15;
#pragma unroll
      for (int kt = 0; kt < 4; ++kt)
#pragma unroll
        for (int r = 0; r < 4; ++r)
          if (kv0 + kt * 16 + g * 4 + r > qg) st[kt][r] = NEG_BIG;
    }

    // ---- online softmax: in-lane reduce + cross-group (masks 16,32) ----
    float mc = NEG_BIG;
#pragma unroll
    for (int kt = 0; kt < 4; ++kt)
#pragma unroll
      for (int r = 0; r < 4; ++r) mc = fmaxf(mc, st[kt][r]);
    mc = fmaxf(mc, __shfl_xor(mc, 16));
    mc = fmaxf(mc, __shfl_xor(mc, 32));
    const float mn = fmaxf(m_run, mc);
    const float alpha = __expf(m_run - mn);
    m_run = mn;
    float ps = 0.f;
#pragma unroll
    for (int kt = 0; kt < 4; ++kt)
#pragma unroll
      for (int r = 0; r < 4; ++r) {
        const float pv = __expf(st[kt][r] - mn);
        st[kt][r] = pv;
        ps += pv;
      }
    ps += __shfl_xor(ps, 16);
    ps += __shfl_xor(ps, 32);
    l_run = l_run * alpha + ps;

    // redistribute alpha (held per q=l15) to accumulator layout (q=g*4+r)
#pragma unroll
    for (int r = 0; r < 4; ++r) {
      const float ar = __shfl(alpha, g * 4 + r, 64);
#pragma unroll
      for (int dt = 0; dt < 4; ++dt) acc[dt][r] *= ar;
    }

    // ---- P -> per-wave LDS, packed b64 (4 bf16 per write) ----
#pragma unroll
    for (int kt = 0; kt < 4; ++kt) {
      union { bf16 h[4]; uint2 u; } pk;
      pk.h[0] = __float2bfloat16(st[kt][0]);
      pk.h[1] = __float2bfloat16(st[kt][1]);
      pk.h[2] = __float2bfloat16(st[kt][2]);
      pk.h[3] = __float2bfloat16(st[kt][3]);
      *reinterpret_cast<uint2*>(&Ps[w][l15][kt * 16 + g * 4]) = pk.u;
    }
    __builtin_amdgcn_sched_barrier(0);

    // ---- O += P V  (A = P rows=q, B = V^T rows=d) ----
#pragma unroll
    for (int kc = 0; kc < 2; ++kc) {
      bf16x8 pf = *reinterpret_cast<const bf16x8*>(&Ps[w][l15][kc * 32 + g * 8]);
#pragma unroll
      for (int dt = 0; dt < 4; ++dt) {
        bf16x8 vf = *reinterpret_cast<const bf16x8*>(&Vt[dt * 16 + l15][kc * 32 + g * 8]);
        acc[dt] = __builtin_amdgcn_mfma_f32_16x16x32_bf16(pf, vf, acc[dt], 0, 0, 0);
      }
    }
  }

  // ---- epilogue: O = acc / l, in-place over this block's Q slab ----
  const float linv = 1.f / l_run;            // for q = qb + l15
  float inv[4];
#pragma unroll
  for (int r = 0; r < 4; ++r) inv[r] = __shfl(linv, g * 4 + r, 64);
  bf16* op = qo + basebh;
#pragma unroll
  for (int dt = 0; dt < 4; ++dt)
#pragma unroll
    for (int r = 0; r < 4; ++r)
      op[(size_t)(qb + g * 4 + r) * 64 + dt * 16 + l15] =
          __float2bfloat16(acc[dt][r] * inv[r]);
}

// ---------- Kernel 3: projection via MFMA ----------
// A = O bf16 BHSD (ws), already bf16 -> raw b128 staging (no cvt).
// W_proj f32 -> bf16 staged transposed, out f32 [8192,1024].
__global__ __launch_bounds__(256)
void proj_f(const bf16* __restrict__ A, const float* __restrict__ W,
            const float* __restrict__ bias, float* __restrict__ out)
{
  __shared__ __align__(16) bf16 As[128][40];
  __shared__ __align__(16) bf16 Bs[128][40];
  const int t   = threadIdx.x;
  const int bn  = blockIdx.x, bm = blockIdx.y;   // (8, 64)
  const int gm0 = bm * 128, gn0 = bn * 128;
  const int w    = t >> 6, lane = t & 63;
  const int g    = lane >> 4, l15 = lane & 15;
  const int wr   = w >> 1, wc = w & 1;

  const int am  = t >> 1, akg = (t & 1) * 2;
  const int bn0 = t & 63;

  const int gr_l = gm0 + am;
  const int bb_l = gr_l >> 11, s_l = gr_l & 2047;

  f32x4 acc[4][4];
#pragma unroll
  for (int i = 0; i < 4; i++)
#pragma unroll
    for (int j = 0; j < 4; j++) acc[i][j] = {0.f, 0.f, 0.f, 0.f};

  for (int kt = 0; kt < 1024; kt += 32) {
    const int c0 = kt + akg * 8;            // 16-aligned: stays within one head's 64 cols
    const int hh = c0 >> 6, dd = c0 & 63;
    const uint4* ap = reinterpret_cast<const uint4*>(
        A + ((size_t)bb_l * 2097152 + (size_t)hh * 131072 + (size_t)s_l * 64 + dd));
    uint4 a0 = ap[0], a1 = ap[1];
    float wb0[8], wb1[8];
#pragma unroll
    for (int kk = 0; kk < 8; kk++) {
      const float* wp = W + (size_t)(kt + w * 8 + kk) * 1024 + gn0 + bn0;
      wb0[kk] = wp[0]; wb1[kk] = wp[64];
    }
    __align__(16) bf16 bb0[8], bb1[8];
#pragma unroll
    for (int i = 0; i < 8; i++) { bb0[i] = __float2bfloat16(wb0[i]); bb1[i] = __float2bfloat16(wb1[i]); }
    __syncthreads();
    *reinterpret_cast<uint4*>(&As[am][swz8(am, akg)])           = a0;
    *reinterpret_cast<uint4*>(&As[am][swz8(am, akg + 1)])       = a1;
    *reinterpret_cast<uint4*>(&Bs[bn0][swz8(bn0, w)])           = *reinterpret_cast<const uint4*>(bb0);
    *reinterpret_cast<uint4*>(&Bs[bn0 + 64][swz8(bn0 + 64, w)]) = *reinterpret_cast<const uint4*>(bb1);
    __syncthreads();

    bf16x8 af[4], bfr[4];
#pragma unroll
    for (int mt = 0; mt < 4; mt++) {
      const int r_ = wr * 64 + mt * 16 + l15;
      af[mt] = *reinterpret_cast<const bf16x8*>(&As[r_][swz8(r_, g)]);
    }
#pragma unroll
    for (int nt = 0; nt < 4; nt++) {
      const int r_ = wc * 64 + nt * 16 + l15;
      bfr[nt] = *reinterpret_cast<const bf16x8*>(&Bs[r_][swz8(r_, g)]);
    }
#pragma unroll
    for (int mt = 0; mt < 4; mt++)
#pragma unroll
      for (int nt = 0; nt < 4; nt++)
        acc[mt][nt] = __builtin_amdgcn_mfma_f32_16x16x32_bf16(af[mt], bfr[nt], acc[mt][nt], 0, 0, 0);
  }

#pragma unroll
  for (int nt = 0; nt < 4; nt++) {
    const int gc = gn0 + wc * 64 + nt * 16 + l15;
    const float bvs = bias[gc];
#pragma unroll
    for (int mt = 0; mt < 4; mt++)
#pragma unroll
      for (int r = 0; r < 4; r++) {
        const int gr = gm0 + wr * 64 + mt * 16 + g * 4 + r;
        out[(size_t)gr * 1024 + gc] = acc[mt][nt][r] + bvs;
      }
  }
}

extern "C" void kernel_launch(void* const* d_in, const int* in_sizes, int n_in,
                              void* d_out, int out_size, void* d_ws, size_t ws_size,
                              hipStream_t stream)
{
  const float *x = nullptr, *W_attn = nullptr, *b_attn = nullptr,
              *W_proj = nullptr, *b_proj = nullptr;
  for (int i = 0; i < n_in; i++) {
    switch (in_sizes[i]) {
      case 8388608: x      = (const float*)d_in[i]; break;  // [4,2048,1024]
      case 3145728: W_attn = (const float*)d_in[i]; break;  // [1024,3072]
      case 3072:    b_attn = (const float*)d_in[i]; break;
      case 1048576: W_proj = (const float*)d_in[i]; break;  // [1024,1024]
      case 1024:    b_proj = (const float*)d_in[i]; break;
      default: break;
    }
  }
  if (!x || !W_attn || !b_attn || !W_proj || !b_proj) {
    x = (const float*)d_in[0]; W_attn = (const float*)d_in[1];
    b_attn = (const float*)d_in[2]; W_proj = (const float*)d_in[3];
    b_proj = (const float*)d_in[4];
  }
  float* out = (float*)d_out;        // 8388608 f32 = 32 MiB

  // Memory plan (inputs never written; ws requirement 16 MiB):
  //   Q -> ws[0:16M)  bf16 BHSD, pre-scaled by 0.125 (later overwritten by O)
  //   K -> d_out bytes [0:16M)  bf16 BHSD   } dead before proj's f32 writes
  //   V -> d_out bytes [16M:32M) bf16 BHDS  }  (transposed for MFMA PV)
  const size_t NE = 8388608;         // bf16 elements per 16 MiB tensor
  bf16* qb = (bf16*)d_ws;
  bf16* kb = (bf16*)d_out;
  bf16* vb = kb + NE;

  qkv_f <<<dim3(24, 64), 256, 0, stream>>>(x, W_attn, b_attn, qb, kb, vb);
  attn_f<<<dim3(32, 16, 4), 256, 0, stream>>>(qb, kb, vb);
  proj_f<<<dim3(8, 64), 256, 0, stream>>>(qb, W_proj, b_proj, out);
}

// Round 4
// 248.482 us; speedup vs baseline: 9.5707x; 1.2140x over previous
//
#include <hip/hip_runtime.h>
#include <hip/hip_bf16.h>

typedef __hip_bfloat16 bf16;
#define NEG_BIG (-3.0e38f)

// MFMA fragment types (gfx950: v_mfma_f32_16x16x32_bf16 takes <8 x bfloat>)
typedef __bf16 bf16x8 __attribute__((ext_vector_type(8)));
typedef float  f32x4  __attribute__((ext_vector_type(4)));

__device__ inline void load8_f32(const float* p, float* o) {
  float4 a = *reinterpret_cast<const float4*>(p);
  float4 b = *reinterpret_cast<const float4*>(p + 4);
  o[0]=a.x; o[1]=a.y; o[2]=a.z; o[3]=a.w;
  o[4]=b.x; o[5]=b.y; o[6]=b.z; o[7]=b.w;
}

// k-granule XOR swizzle: breaks the 8-way bank conflict of n-row b128 writes
// at row-stride 80B. Element offset of 8-elem granule kg within a row.
__device__ inline int swz8(int row, int kg) { return ((kg ^ ((row >> 3) & 3)) << 3); }

// ---------- Kernel 1: QKV GEMM via MFMA ----------
// X[8192,1024]f32 @ W[1024,3072]f32 + b.  128x128 tile, 4 waves 2x2 (64x64/wave).
// Q is stored PRE-SCALED by 1/sqrt(HEAD_DIM)=0.125 (folded out of attention).
// Q -> ws bf16 BHSD; K -> d_out[0:16M) bf16 BHSD; V -> d_out[16M:32M) bf16 BHDS.
__global__ __launch_bounds__(256)
void qkv_f(const float* __restrict__ X, const float* __restrict__ W,
           const float* __restrict__ bias,
           bf16* __restrict__ q, bf16* __restrict__ k, bf16* __restrict__ v)
{
  __shared__ __align__(16) bf16 As[128][40];   // row = m, 32 k + pad
  __shared__ __align__(16) bf16 Bs[128][40];   // row = n, 32 k + pad
  const int t   = threadIdx.x;
  const int bn  = blockIdx.x, bm = blockIdx.y;   // (24, 64)
  const int gm0 = bm * 128, gn0 = bn * 128;
  const int w    = t >> 6, lane = t & 63;
  const int g    = lane >> 4, l15 = lane & 15;
  const int wr   = w >> 1, wc = w & 1;

  const int am  = t >> 1, akg = (t & 1) * 2;   // A staging: row am, granules akg,akg+1
  const int bn0 = t & 63;                       // B staging: rows bn0,bn0+64, granule w

  f32x4 acc[4][4];
#pragma unroll
  for (int i = 0; i < 4; i++)
#pragma unroll
    for (int j = 0; j < 4; j++) acc[i][j] = {0.f, 0.f, 0.f, 0.f};

  for (int kt = 0; kt < 1024; kt += 32) {
    float a32[16];
    load8_f32(X + (size_t)(gm0 + am) * 1024 + kt + akg * 8, a32);
    load8_f32(X + (size_t)(gm0 + am) * 1024 + kt + akg * 8 + 8, a32 + 8);
    float wb0[8], wb1[8];
#pragma unroll
    for (int kk = 0; kk < 8; kk++) {
      const float* wp = W + (size_t)(kt + w * 8 + kk) * 3072 + gn0 + bn0;
      wb0[kk] = wp[0]; wb1[kk] = wp[64];
    }
    __align__(16) bf16 ab[16], bb0[8], bb1[8];
#pragma unroll
    for (int i = 0; i < 16; i++) ab[i] = __float2bfloat16(a32[i]);
#pragma unroll
    for (int i = 0; i < 8; i++) { bb0[i] = __float2bfloat16(wb0[i]); bb1[i] = __float2bfloat16(wb1[i]); }
    __syncthreads();   // previous iteration's fragment reads done
    *reinterpret_cast<uint4*>(&As[am][swz8(am, akg)])           = reinterpret_cast<const uint4*>(ab)[0];
    *reinterpret_cast<uint4*>(&As[am][swz8(am, akg + 1)])       = reinterpret_cast<const uint4*>(ab)[1];
    *reinterpret_cast<uint4*>(&Bs[bn0][swz8(bn0, w)])           = *reinterpret_cast<const uint4*>(bb0);
    *reinterpret_cast<uint4*>(&Bs[bn0 + 64][swz8(bn0 + 64, w)]) = *reinterpret_cast<const uint4*>(bb1);
    __syncthreads();

    bf16x8 af[4], bfr[4];
#pragma unroll
    for (int mt = 0; mt < 4; mt++) {
      const int r_ = wr * 64 + mt * 16 + l15;
      af[mt] = *reinterpret_cast<const bf16x8*>(&As[r_][swz8(r_, g)]);
    }
#pragma unroll
    for (int nt = 0; nt < 4; nt++) {
      const int r_ = wc * 64 + nt * 16 + l15;
      bfr[nt] = *reinterpret_cast<const bf16x8*>(&Bs[r_][swz8(r_, g)]);
    }
#pragma unroll
    for (int mt = 0; mt < 4; mt++)
#pragma unroll
      for (int nt = 0; nt < 4; nt++)
        acc[mt][nt] = __builtin_amdgcn_mfma_f32_16x16x32_bf16(af[mt], bfr[nt], acc[mt][nt], 0, 0, 0);
  }

  // Epilogue: C layout row = g*4+r, col = l15. Scatter to Q/K/V (V transposed).
#pragma unroll
  for (int nt = 0; nt < 4; nt++) {
    const int gc  = gn0 + wc * 64 + nt * 16 + l15;   // never crosses Q/K/V or head boundary
    const float bvs = bias[gc];
    const int which = gc >> 10;
    const int cc = gc & 1023;
    const int hh = cc >> 6, d = cc & 63;
    bf16* dst = (which == 0) ? q : ((which == 1) ? k : v);
#pragma unroll
    for (int mt = 0; mt < 4; mt++)
#pragma unroll
      for (int r = 0; r < 4; r++) {
        const int gr = gm0 + wr * 64 + mt * 16 + g * 4 + r;
        const int bb = gr >> 11, s = gr & 2047;
        float val = acc[mt][nt][r] + bvs;
        if (which == 0) val *= 0.125f;   // fold softmax scale into Q
        if (which == 2)
          dst[((size_t)(bb * 16 + hh) * 64 + d) * 2048 + s] = __float2bfloat16(val);
        else
          dst[((size_t)(bb * 16 + hh) * 2048 + s) * 64 + d] = __float2bfloat16(val);
      }
  }
}

// ---------- Kernel 2: causal flash attention via MFMA, swapped QK^T ----------
// Triangular-paired + XCD-local grid: 1024 blocks (all co-resident, 4/CU).
// Block = (hb pair, qt0); processes q-tile 31-qt0 then qt0 => exactly 34
// KV-tiles per block (perfect balance). Decode puts the 16 blocks of each
// (b,h) on ONE XCD (hb = (f&7) + 8*(f>>7)) so that XCD's L2 working set is
// 8 heads x 512KB = 4MB: K/V re-reads become L2 hits instead of HBM/L3.
// Per-wave body unchanged: swapped mfma(K,Q), in-lane softmax, reg prefetch.
__global__ __launch_bounds__(256)
void attn_f(bf16* __restrict__ qo, const bf16* __restrict__ k, const bf16* __restrict__ v)
{
  __shared__ __align__(16) bf16 Ks[64][72];     // K tile, row = k, col = d
  __shared__ __align__(16) bf16 Vt[64][72];     // V tile, row = d, col = k
  __shared__ __align__(16) bf16 Ps[4][16][72];  // per-wave P, row = q, col = k

  const int t    = threadIdx.x;
  const int f    = blockIdx.x;            // 0..1023
  const int xcd  = f & 7;
  const int j    = f >> 3;                // 0..127
  const int hb   = xcd + 8 * (j >> 4);    // 0..63, fixed per XCD
  const int qt0  = j & 15;                // 0..15
  const int b    = hb >> 4, h = hb & 15;
  const size_t basebh = (size_t)(b * 16 + h) * 2048 * 64;

  const int w    = t >> 6;
  const int lane = t & 63;
  const int g    = lane >> 4;
  const int l15  = lane & 15;

  const int sr = t >> 3;          // staging row 0..31
  const int sc = (t & 7) * 8;     // staging col (elements)
  const bf16* kbase = k + basebh;
  const bf16* vbase = v + basebh;

#pragma unroll 1
  for (int pass = 0; pass < 2; ++pass) {
    const int qt = pass ? qt0 : (31 - qt0);
    const int qb = qt * 64 + w * 16;

    // Q B-fragments for this pass (operand order in mfma is swapped)
    const bf16* qrow = qo + basebh + (size_t)(qb + l15) * 64;
    bf16x8 qf0 = *reinterpret_cast<const bf16x8*>(qrow + g * 8);
    bf16x8 qf1 = *reinterpret_cast<const bf16x8*>(qrow + 32 + g * 8);

    f32x4 acc[4] = {{0,0,0,0},{0,0,0,0},{0,0,0,0},{0,0,0,0}};
    float m_run = NEG_BIG, l_run = 0.f;   // canonical per-lane q = qb + l15

    uint4 kreg0, kreg1, vreg0, vreg1;
    {
      kreg0 = *reinterpret_cast<const uint4*>(kbase + (size_t)(sr) * 64 + sc);
      kreg1 = *reinterpret_cast<const uint4*>(kbase + (size_t)(32 + sr) * 64 + sc);
      vreg0 = *reinterpret_cast<const uint4*>(vbase + (size_t)sr * 2048 + sc);
      vreg1 = *reinterpret_cast<const uint4*>(vbase + (size_t)(32 + sr) * 2048 + sc);
    }

    for (int ct = 0; ct <= qt; ++ct) {
      const int kv0 = ct * 64;
      __syncthreads();              // all waves done reading previous tile
      *reinterpret_cast<uint4*>(&Ks[sr][sc])      = kreg0;
      *reinterpret_cast<uint4*>(&Ks[32 + sr][sc]) = kreg1;
      *reinterpret_cast<uint4*>(&Vt[sr][sc])      = vreg0;
      *reinterpret_cast<uint4*>(&Vt[32 + sr][sc]) = vreg1;
      if (ct < qt) {                // prefetch next tile (hides under compute)
        const int nv0 = kv0 + 64;
        kreg0 = *reinterpret_cast<const uint4*>(kbase + (size_t)(nv0 + sr) * 64 + sc);
        kreg1 = *reinterpret_cast<const uint4*>(kbase + (size_t)(nv0 + 32 + sr) * 64 + sc);
        vreg0 = *reinterpret_cast<const uint4*>(vbase + (size_t)sr * 2048 + nv0 + sc);
        vreg1 = *reinterpret_cast<const uint4*>(vbase + (size_t)(32 + sr) * 2048 + nv0 + sc);
      }
      __syncthreads();

      // ---- S^T tile: st[kt][r] = S[k = kv0+kt*16+g*4+r][q = qb+l15] ----
      f32x4 st[4];
#pragma unroll
      for (int kt = 0; kt < 4; ++kt) {
        const int kr = kt * 16 + l15;
        bf16x8 kf0 = *reinterpret_cast<const bf16x8*>(&Ks[kr][g * 8]);
        bf16x8 kf1 = *reinterpret_cast<const bf16x8*>(&Ks[kr][32 + g * 8]);
        f32x4 c4 = {0,0,0,0};
        c4 = __builtin_amdgcn_mfma_f32_16x16x32_bf16(kf0, qf0, c4, 0, 0, 0);
        c4 = __builtin_amdgcn_mfma_f32_16x16x32_bf16(kf1, qf1, c4, 0, 0, 0);
        st[kt] = c4;
      }
      if (ct == qt) {               // causal mask, diagonal tile only
        const int qg = qb + l15;
#pragma unroll
        for (int kt = 0; kt < 4; ++kt)
#pragma unroll
          for (int r = 0; r < 4; ++r)
            if (kv0 + kt * 16 + g * 4 + r > qg) st[kt][r] = NEG_BIG;
      }

      // ---- online softmax: in-lane reduce + cross-group (masks 16,32) ----
      float mc = NEG_BIG;
#pragma unroll
      for (int kt = 0; kt < 4; ++kt)
#pragma unroll
        for (int r = 0; r < 4; ++r) mc = fmaxf(mc, st[kt][r]);
      mc = fmaxf(mc, __shfl_xor(mc, 16));
      mc = fmaxf(mc, __shfl_xor(mc, 32));
      const float mn = fmaxf(m_run, mc);
      const float alpha = __expf(m_run - mn);
      m_run = mn;
      float ps = 0.f;
#pragma unroll
      for (int kt = 0; kt < 4; ++kt)
#pragma unroll
        for (int r = 0; r < 4; ++r) {
          const float pv = __expf(st[kt][r] - mn);
          st[kt][r] = pv;
          ps += pv;
        }
      ps += __shfl_xor(ps, 16);
      ps += __shfl_xor(ps, 32);
      l_run = l_run * alpha + ps;

      // redistribute alpha (held per q=l15) to accumulator layout (q=g*4+r)
#pragma unroll
      for (int r = 0; r < 4; ++r) {
        const float ar = __shfl(alpha, g * 4 + r, 64);
#pragma unroll
        for (int dt = 0; dt < 4; ++dt) acc[dt][r] *= ar;
      }

      // ---- P -> per-wave LDS, packed b64 (4 bf16 per write) ----
#pragma unroll
      for (int kt = 0; kt < 4; ++kt) {
        union { bf16 hh[4]; uint2 u; } pk;
        pk.hh[0] = __float2bfloat16(st[kt][0]);
        pk.hh[1] = __float2bfloat16(st[kt][1]);
        pk.hh[2] = __float2bfloat16(st[kt][2]);
        pk.hh[3] = __float2bfloat16(st[kt][3]);
        *reinterpret_cast<uint2*>(&Ps[w][l15][kt * 16 + g * 4]) = pk.u;
      }
      __builtin_amdgcn_sched_barrier(0);

      // ---- O += P V  (A = P rows=q, B = V^T rows=d) ----
#pragma unroll
      for (int kc = 0; kc < 2; ++kc) {
        bf16x8 pf = *reinterpret_cast<const bf16x8*>(&Ps[w][l15][kc * 32 + g * 8]);
#pragma unroll
        for (int dt = 0; dt < 4; ++dt) {
          bf16x8 vf = *reinterpret_cast<const bf16x8*>(&Vt[dt * 16 + l15][kc * 32 + g * 8]);
          acc[dt] = __builtin_amdgcn_mfma_f32_16x16x32_bf16(pf, vf, acc[dt], 0, 0, 0);
        }
      }
    }

    // ---- epilogue: O = acc / l, in-place over this pass's Q slab ----
    const float linv = 1.f / l_run;            // for q = qb + l15
    float inv[4];
#pragma unroll
    for (int r = 0; r < 4; ++r) inv[r] = __shfl(linv, g * 4 + r, 64);
    bf16* op = qo + basebh;
#pragma unroll
    for (int dt = 0; dt < 4; ++dt)
#pragma unroll
      for (int r = 0; r < 4; ++r)
        op[(size_t)(qb + g * 4 + r) * 64 + dt * 16 + l15] =
            __float2bfloat16(acc[dt][r] * inv[r]);
  }
}

// ---------- Kernel 3: projection via MFMA ----------
// A = O bf16 BHSD (ws), already bf16 -> raw b128 staging (no cvt).
// W_proj f32 -> bf16 staged transposed, out f32 [8192,1024].
__global__ __launch_bounds__(256)
void proj_f(const bf16* __restrict__ A, const float* __restrict__ W,
            const float* __restrict__ bias, float* __restrict__ out)
{
  __shared__ __align__(16) bf16 As[128][40];
  __shared__ __align__(16) bf16 Bs[128][40];
  const int t   = threadIdx.x;
  const int bn  = blockIdx.x, bm = blockIdx.y;   // (8, 64)
  const int gm0 = bm * 128, gn0 = bn * 128;
  const int w    = t >> 6, lane = t & 63;
  const int g    = lane >> 4, l15 = lane & 15;
  const int wr   = w >> 1, wc = w & 1;

  const int am  = t >> 1, akg = (t & 1) * 2;
  const int bn0 = t & 63;

  const int gr_l = gm0 + am;
  const int bb_l = gr_l >> 11, s_l = gr_l & 2047;

  f32x4 acc[4][4];
#pragma unroll
  for (int i = 0; i < 4; i++)
#pragma unroll
    for (int j = 0; j < 4; j++) acc[i][j] = {0.f, 0.f, 0.f, 0.f};

  for (int kt = 0; kt < 1024; kt += 32) {
    const int c0 = kt + akg * 8;            // 16-aligned: stays within one head's 64 cols
    const int hh = c0 >> 6, dd = c0 & 63;
    const uint4* ap = reinterpret_cast<const uint4*>(
        A + ((size_t)bb_l * 2097152 + (size_t)hh * 131072 + (size_t)s_l * 64 + dd));
    uint4 a0 = ap[0], a1 = ap[1];
    float wb0[8], wb1[8];
#pragma unroll
    for (int kk = 0; kk < 8; kk++) {
      const float* wp = W + (size_t)(kt + w * 8 + kk) * 1024 + gn0 + bn0;
      wb0[kk] = wp[0]; wb1[kk] = wp[64];
    }
    __align__(16) bf16 bb0[8], bb1[8];
#pragma unroll
    for (int i = 0; i < 8; i++) { bb0[i] = __float2bfloat16(wb0[i]); bb1[i] = __float2bfloat16(wb1[i]); }
    __syncthreads();
    *reinterpret_cast<uint4*>(&As[am][swz8(am, akg)])           = a0;
    *reinterpret_cast<uint4*>(&As[am][swz8(am, akg + 1)])       = a1;
    *reinterpret_cast<uint4*>(&Bs[bn0][swz8(bn0, w)])           = *reinterpret_cast<const uint4*>(bb0);
    *reinterpret_cast<uint4*>(&Bs[bn0 + 64][swz8(bn0 + 64, w)]) = *reinterpret_cast<const uint4*>(bb1);
    __syncthreads();

    bf16x8 af[4], bfr[4];
#pragma unroll
    for (int mt = 0; mt < 4; mt++) {
      const int r_ = wr * 64 + mt * 16 + l15;
      af[mt] = *reinterpret_cast<const bf16x8*>(&As[r_][swz8(r_, g)]);
    }
#pragma unroll
    for (int nt = 0; nt < 4; nt++) {
      const int r_ = wc * 64 + nt * 16 + l15;
      bfr[nt] = *reinterpret_cast<const bf16x8*>(&Bs[r_][swz8(r_, g)]);
    }
#pragma unroll
    for (int mt = 0; mt < 4; mt++)
#pragma unroll
      for (int nt = 0; nt < 4; nt++)
        acc[mt][nt] = __builtin_amdgcn_mfma_f32_16x16x32_bf16(af[mt], bfr[nt], acc[mt][nt], 0, 0, 0);
  }

#pragma unroll
  for (int nt = 0; nt < 4; nt++) {
    const int gc = gn0 + wc * 64 + nt * 16 + l15;
    const float bvs = bias[gc];
#pragma unroll
    for (int mt = 0; mt < 4; mt++)
#pragma unroll
      for (int r = 0; r < 4; r++) {
        const int gr = gm0 + wr * 64 + mt * 16 + g * 4 + r;
        out[(size_t)gr * 1024 + gc] = acc[mt][nt][r] + bvs;
      }
  }
}

extern "C" void kernel_launch(void* const* d_in, const int* in_sizes, int n_in,
                              void* d_out, int out_size, void* d_ws, size_t ws_size,
                              hipStream_t stream)
{
  const float *x = nullptr, *W_attn = nullptr, *b_attn = nullptr,
              *W_proj = nullptr, *b_proj = nullptr;
  for (int i = 0; i < n_in; i++) {
    switch (in_sizes[i]) {
      case 8388608: x      = (const float*)d_in[i]; break;  // [4,2048,1024]
      case 3145728: W_attn = (const float*)d_in[i]; break;  // [1024,3072]
      case 3072:    b_attn = (const float*)d_in[i]; break;
      case 1048576: W_proj = (const float*)d_in[i]; break;  // [1024,1024]
      case 1024:    b_proj = (const float*)d_in[i]; break;
      default: break;
    }
  }
  if (!x || !W_attn || !b_attn || !W_proj || !b_proj) {
    x = (const float*)d_in[0]; W_attn = (const float*)d_in[1];
    b_attn = (const float*)d_in[2]; W_proj = (const float*)d_in[3];
    b_proj = (const float*)d_in[4];
  }
  float* out = (float*)d_out;        // 8388608 f32 = 32 MiB

  // Memory plan (inputs never written; ws requirement 16 MiB):
  //   Q -> ws[0:16M)  bf16 BHSD, pre-scaled by 0.125 (later overwritten by O)
  //   K -> d_out bytes [0:16M)  bf16 BHSD   } dead before proj's f32 writes
  //   V -> d_out bytes [16M:32M) bf16 BHDS  }  (transposed for MFMA PV)
  const size_t NE = 8388608;         // bf16 elements per 16 MiB tensor
  bf16* qb = (bf16*)d_ws;
  bf16* kb = (bf16*)d_out;
  bf16* vb = kb + NE;

  qkv_f <<<dim3(24, 64), 256, 0, stream>>>(x, W_attn, b_attn, qb, kb, vb);
  attn_f<<<dim3(1024), 256, 0, stream>>>(qb, kb, vb);
  proj_f<<<dim3(8, 64), 256, 0, stream>>>(qb, W_proj, b_proj, out);
}

// Round 5
// 221.107 us; speedup vs baseline: 10.7557x; 1.1238x over previous
//
#include <hip/hip_runtime.h>
#include <hip/hip_bf16.h>

typedef __hip_bfloat16 bf16;
#define NEG_BIG (-3.0e38f)

// MFMA fragment types (gfx950: v_mfma_f32_16x16x32_bf16 takes <8 x bfloat>)
typedef __bf16 bf16x8 __attribute__((ext_vector_type(8)));
typedef float  f32x4  __attribute__((ext_vector_type(4)));

__device__ inline void load8_f32(const float* p, float* o) {
  float4 a = *reinterpret_cast<const float4*>(p);
  float4 b = *reinterpret_cast<const float4*>(p + 4);
  o[0]=a.x; o[1]=a.y; o[2]=a.z; o[3]=a.w;
  o[4]=b.x; o[5]=b.y; o[6]=b.z; o[7]=b.w;
}

// k-granule XOR swizzle: breaks the 8-way bank conflict of n-row b128 writes
// at row-stride 80B. Element offset of 8-elem granule kg within a row.
__device__ inline int swz8(int row, int kg) { return ((kg ^ ((row >> 3) & 3)) << 3); }

// ---------- Kernel 1: QKV GEMM via MFMA, prefetch-pipelined + XCD-local ----------
// X[8192,1024]f32 @ W[1024,3072]f32 + b.  128x128 tile, 4 waves 2x2 (64x64/wave).
// Flat grid 1536; decode: xcd=f&7, bm=xcd*8+(j&7), bn=j>>3. Each XCD owns an
// 8-bm slice (4MB of X = one L2, resident all kernel); consecutive blocks on
// an XCD share the same W panel. Next iteration's global loads issue before
// the MFMA block (latency hides under compute, T14).
// Q is stored PRE-SCALED by 1/sqrt(HEAD_DIM)=0.125 (folded out of attention).
// Q -> ws bf16 BHSD; K -> d_out[0:16M) bf16 BHSD; V -> d_out[16M:32M) bf16 BHDS.
__global__ __launch_bounds__(256)
void qkv_f(const float* __restrict__ X, const float* __restrict__ W,
           const float* __restrict__ bias,
           bf16* __restrict__ q, bf16* __restrict__ k, bf16* __restrict__ v)
{
  __shared__ __align__(16) bf16 As[128][40];   // row = m, 32 k + pad
  __shared__ __align__(16) bf16 Bs[128][40];   // row = n, 32 k + pad
  const int t   = threadIdx.x;
  const int f   = blockIdx.x;               // 0..1535
  const int xcd = f & 7, j = f >> 3;        // j 0..191
  const int bm  = xcd * 8 + (j & 7);        // 0..63
  const int bn  = j >> 3;                   // 0..23
  const int gm0 = bm * 128, gn0 = bn * 128;
  const int w    = t >> 6, lane = t & 63;
  const int g    = lane >> 4, l15 = lane & 15;
  const int wr   = w >> 1, wc = w & 1;

  const int am  = t >> 1, akg = (t & 1) * 2;   // A staging: row am, granules akg,akg+1
  const int bn0 = t & 63;                       // B staging: rows bn0,bn0+64, granule w

  f32x4 acc[4][4];
#pragma unroll
  for (int i = 0; i < 4; i++)
#pragma unroll
    for (int jj = 0; jj < 4; jj++) acc[i][jj] = {0.f, 0.f, 0.f, 0.f};

  const float* aptr = X + (size_t)(gm0 + am) * 1024 + akg * 8;
  const float* wptr = W + (size_t)(w * 8) * 3072 + gn0 + bn0;

  float a32[16], wb0[8], wb1[8];
  load8_f32(aptr, a32);
  load8_f32(aptr + 8, a32 + 8);
#pragma unroll
  for (int kk = 0; kk < 8; kk++) { wb0[kk] = wptr[kk * 3072]; wb1[kk] = wptr[kk * 3072 + 64]; }

  for (int kt = 0; kt < 1024; kt += 32) {
    __align__(16) bf16 ab[16], bb0[8], bb1[8];
#pragma unroll
    for (int i = 0; i < 16; i++) ab[i] = __float2bfloat16(a32[i]);
#pragma unroll
    for (int i = 0; i < 8; i++) { bb0[i] = __float2bfloat16(wb0[i]); bb1[i] = __float2bfloat16(wb1[i]); }
    __syncthreads();   // previous iteration's fragment reads done
    *reinterpret_cast<uint4*>(&As[am][swz8(am, akg)])           = reinterpret_cast<const uint4*>(ab)[0];
    *reinterpret_cast<uint4*>(&As[am][swz8(am, akg + 1)])       = reinterpret_cast<const uint4*>(ab)[1];
    *reinterpret_cast<uint4*>(&Bs[bn0][swz8(bn0, w)])           = *reinterpret_cast<const uint4*>(bb0);
    *reinterpret_cast<uint4*>(&Bs[bn0 + 64][swz8(bn0 + 64, w)]) = *reinterpret_cast<const uint4*>(bb1);
    if (kt + 32 < 1024) {            // prefetch next K-slice (hides under MFMA)
      aptr += 32; wptr += 32 * 3072;
      load8_f32(aptr, a32);
      load8_f32(aptr + 8, a32 + 8);
#pragma unroll
      for (int kk = 0; kk < 8; kk++) { wb0[kk] = wptr[kk * 3072]; wb1[kk] = wptr[kk * 3072 + 64]; }
    }
    __syncthreads();

    bf16x8 af[4], bfr[4];
#pragma unroll
    for (int mt = 0; mt < 4; mt++) {
      const int r_ = wr * 64 + mt * 16 + l15;
      af[mt] = *reinterpret_cast<const bf16x8*>(&As[r_][swz8(r_, g)]);
    }
#pragma unroll
    for (int nt = 0; nt < 4; nt++) {
      const int r_ = wc * 64 + nt * 16 + l15;
      bfr[nt] = *reinterpret_cast<const bf16x8*>(&Bs[r_][swz8(r_, g)]);
    }
#pragma unroll
    for (int mt = 0; mt < 4; mt++)
#pragma unroll
      for (int nt = 0; nt < 4; nt++)
        acc[mt][nt] = __builtin_amdgcn_mfma_f32_16x16x32_bf16(af[mt], bfr[nt], acc[mt][nt], 0, 0, 0);
  }

  // Epilogue: C layout row = g*4+r, col = l15. Scatter to Q/K/V (V transposed).
#pragma unroll
  for (int nt = 0; nt < 4; nt++) {
    const int gc  = gn0 + wc * 64 + nt * 16 + l15;   // never crosses Q/K/V or head boundary
    const float bvs = bias[gc];
    const int which = gc >> 10;
    const int cc = gc & 1023;
    const int hh = cc >> 6, d = cc & 63;
    bf16* dst = (which == 0) ? q : ((which == 1) ? k : v);
#pragma unroll
    for (int mt = 0; mt < 4; mt++)
#pragma unroll
      for (int r = 0; r < 4; r++) {
        const int gr = gm0 + wr * 64 + mt * 16 + g * 4 + r;
        const int bb = gr >> 11, s = gr & 2047;
        float val = acc[mt][nt][r] + bvs;
        if (which == 0) val *= 0.125f;   // fold softmax scale into Q
        if (which == 2)
          dst[((size_t)(bb * 16 + hh) * 64 + d) * 2048 + s] = __float2bfloat16(val);
        else
          dst[((size_t)(bb * 16 + hh) * 2048 + s) * 64 + d] = __float2bfloat16(val);
      }
  }
}

// ---------- Kernel 2: causal flash attention via MFMA, swapped QK^T ----------
// Triangular-paired + XCD-local grid: 1024 blocks (all co-resident, 4/CU).
// Block = (hb pair, qt0); processes q-tile 31-qt0 then qt0 => exactly 34
// KV-tiles per block (perfect balance). Decode puts the 16 blocks of each
// (b,h) on ONE XCD (hb = (f&7) + 8*(f>>7)) so that XCD's L2 working set is
// 8 heads x 512KB = 4MB: K/V re-reads become L2 hits instead of HBM/L3.
// Per-wave body: swapped mfma(K,Q), in-lane softmax, reg prefetch.
__global__ __launch_bounds__(256)
void attn_f(bf16* __restrict__ qo, const bf16* __restrict__ k, const bf16* __restrict__ v)
{
  __shared__ __align__(16) bf16 Ks[64][72];     // K tile, row = k, col = d
  __shared__ __align__(16) bf16 Vt[64][72];     // V tile, row = d, col = k
  __shared__ __align__(16) bf16 Ps[4][16][72];  // per-wave P, row = q, col = k

  const int t    = threadIdx.x;
  const int f    = blockIdx.x;            // 0..1023
  const int xcd  = f & 7;
  const int j    = f >> 3;                // 0..127
  const int hb   = xcd + 8 * (j >> 4);    // 0..63, fixed per XCD
  const int qt0  = j & 15;                // 0..15
  const int b    = hb >> 4, h = hb & 15;
  const size_t basebh = (size_t)(b * 16 + h) * 2048 * 64;

  const int w    = t >> 6;
  const int lane = t & 63;
  const int g    = lane >> 4;
  const int l15  = lane & 15;

  const int sr = t >> 3;          // staging row 0..31
  const int sc = (t & 7) * 8;     // staging col (elements)
  const bf16* kbase = k + basebh;
  const bf16* vbase = v + basebh;

#pragma unroll 1
  for (int pass = 0; pass < 2; ++pass) {
    const int qt = pass ? qt0 : (31 - qt0);
    const int qb = qt * 64 + w * 16;

    // Q B-fragments for this pass (operand order in mfma is swapped)
    const bf16* qrow = qo + basebh + (size_t)(qb + l15) * 64;
    bf16x8 qf0 = *reinterpret_cast<const bf16x8*>(qrow + g * 8);
    bf16x8 qf1 = *reinterpret_cast<const bf16x8*>(qrow + 32 + g * 8);

    f32x4 acc[4] = {{0,0,0,0},{0,0,0,0},{0,0,0,0},{0,0,0,0}};
    float m_run = NEG_BIG, l_run = 0.f;   // canonical per-lane q = qb + l15

    uint4 kreg0, kreg1, vreg0, vreg1;
    {
      kreg0 = *reinterpret_cast<const uint4*>(kbase + (size_t)(sr) * 64 + sc);
      kreg1 = *reinterpret_cast<const uint4*>(kbase + (size_t)(32 + sr) * 64 + sc);
      vreg0 = *reinterpret_cast<const uint4*>(vbase + (size_t)sr * 2048 + sc);
      vreg1 = *reinterpret_cast<const uint4*>(vbase + (size_t)(32 + sr) * 2048 + sc);
    }

    for (int ct = 0; ct <= qt; ++ct) {
      const int kv0 = ct * 64;
      __syncthreads();              // all waves done reading previous tile
      *reinterpret_cast<uint4*>(&Ks[sr][sc])      = kreg0;
      *reinterpret_cast<uint4*>(&Ks[32 + sr][sc]) = kreg1;
      *reinterpret_cast<uint4*>(&Vt[sr][sc])      = vreg0;
      *reinterpret_cast<uint4*>(&Vt[32 + sr][sc]) = vreg1;
      if (ct < qt) {                // prefetch next tile (hides under compute)
        const int nv0 = kv0 + 64;
        kreg0 = *reinterpret_cast<const uint4*>(kbase + (size_t)(nv0 + sr) * 64 + sc);
        kreg1 = *reinterpret_cast<const uint4*>(kbase + (size_t)(nv0 + 32 + sr) * 64 + sc);
        vreg0 = *reinterpret_cast<const uint4*>(vbase + (size_t)sr * 2048 + nv0 + sc);
        vreg1 = *reinterpret_cast<const uint4*>(vbase + (size_t)(32 + sr) * 2048 + nv0 + sc);
      }
      __syncthreads();

      // ---- S^T tile: st[kt][r] = S[k = kv0+kt*16+g*4+r][q = qb+l15] ----
      f32x4 st[4];
#pragma unroll
      for (int kt = 0; kt < 4; ++kt) {
        const int kr = kt * 16 + l15;
        bf16x8 kf0 = *reinterpret_cast<const bf16x8*>(&Ks[kr][g * 8]);
        bf16x8 kf1 = *reinterpret_cast<const bf16x8*>(&Ks[kr][32 + g * 8]);
        f32x4 c4 = {0,0,0,0};
        c4 = __builtin_amdgcn_mfma_f32_16x16x32_bf16(kf0, qf0, c4, 0, 0, 0);
        c4 = __builtin_amdgcn_mfma_f32_16x16x32_bf16(kf1, qf1, c4, 0, 0, 0);
        st[kt] = c4;
      }
      if (ct == qt) {               // causal mask, diagonal tile only
        const int qg = qb + l15;
#pragma unroll
        for (int kt = 0; kt < 4; ++kt)
#pragma unroll
          for (int r = 0; r < 4; ++r)
            if (kv0 + kt * 16 + g * 4 + r > qg) st[kt][r] = NEG_BIG;
      }

      // ---- online softmax: in-lane reduce + cross-group (masks 16,32) ----
      float mc = NEG_BIG;
#pragma unroll
      for (int kt = 0; kt < 4; ++kt)
#pragma unroll
        for (int r = 0; r < 4; ++r) mc = fmaxf(mc, st[kt][r]);
      mc = fmaxf(mc, __shfl_xor(mc, 16));
      mc = fmaxf(mc, __shfl_xor(mc, 32));
      const float mn = fmaxf(m_run, mc);
      const float alpha = __expf(m_run - mn);
      m_run = mn;
      float ps = 0.f;
#pragma unroll
      for (int kt = 0; kt < 4; ++kt)
#pragma unroll
        for (int r = 0; r < 4; ++r) {
          const float pv = __expf(st[kt][r] - mn);
          st[kt][r] = pv;
          ps += pv;
        }
      ps += __shfl_xor(ps, 16);
      ps += __shfl_xor(ps, 32);
      l_run = l_run * alpha + ps;

      // redistribute alpha (held per q=l15) to accumulator layout (q=g*4+r)
#pragma unroll
      for (int r = 0; r < 4; ++r) {
        const float ar = __shfl(alpha, g * 4 + r, 64);
#pragma unroll
        for (int dt = 0; dt < 4; ++dt) acc[dt][r] *= ar;
      }

      // ---- P -> per-wave LDS, packed b64 (4 bf16 per write) ----
#pragma unroll
      for (int kt = 0; kt < 4; ++kt) {
        union { bf16 hh[4]; uint2 u; } pk;
        pk.hh[0] = __float2bfloat16(st[kt][0]);
        pk.hh[1] = __float2bfloat16(st[kt][1]);
        pk.hh[2] = __float2bfloat16(st[kt][2]);
        pk.hh[3] = __float2bfloat16(st[kt][3]);
        *reinterpret_cast<uint2*>(&Ps[w][l15][kt * 16 + g * 4]) = pk.u;
      }
      __builtin_amdgcn_sched_barrier(0);

      // ---- O += P V  (A = P rows=q, B = V^T rows=d) ----
#pragma unroll
      for (int kc = 0; kc < 2; ++kc) {
        bf16x8 pf = *reinterpret_cast<const bf16x8*>(&Ps[w][l15][kc * 32 + g * 8]);
#pragma unroll
        for (int dt = 0; dt < 4; ++dt) {
          bf16x8 vf = *reinterpret_cast<const bf16x8*>(&Vt[dt * 16 + l15][kc * 32 + g * 8]);
          acc[dt] = __builtin_amdgcn_mfma_f32_16x16x32_bf16(pf, vf, acc[dt], 0, 0, 0);
        }
      }
    }

    // ---- epilogue: O = acc / l, in-place over this pass's Q slab ----
    const float linv = 1.f / l_run;            // for q = qb + l15
    float inv[4];
#pragma unroll
    for (int r = 0; r < 4; ++r) inv[r] = __shfl(linv, g * 4 + r, 64);
    bf16* op = qo + basebh;
#pragma unroll
    for (int dt = 0; dt < 4; ++dt)
#pragma unroll
      for (int r = 0; r < 4; ++r)
        op[(size_t)(qb + g * 4 + r) * 64 + dt * 16 + l15] =
            __float2bfloat16(acc[dt][r] * inv[r]);
  }
}

// ---------- Kernel 3: projection via MFMA, prefetch-pipelined + XCD-local ----------
// A = O bf16 BHSD (ws), already bf16 -> raw b128 staging (no cvt).
// W_proj f32 -> bf16 staged transposed, out f32 [8192,1024].
__global__ __launch_bounds__(256)
void proj_f(const bf16* __restrict__ A, const float* __restrict__ W,
            const float* __restrict__ bias, float* __restrict__ out)
{
  __shared__ __align__(16) bf16 As[128][40];
  __shared__ __align__(16) bf16 Bs[128][40];
  const int t   = threadIdx.x;
  const int f   = blockIdx.x;               // 0..511
  const int xcd = f & 7, j = f >> 3;        // j 0..63
  const int bm  = xcd * 8 + (j & 7);        // 0..63
  const int bn  = j >> 3;                   // 0..7
  const int gm0 = bm * 128, gn0 = bn * 128;
  const int w    = t >> 6, lane = t & 63;
  const int g    = lane >> 4, l15 = lane & 15;
  const int wr   = w >> 1, wc = w & 1;

  const int am  = t >> 1, akg = (t & 1) * 2;
  const int bn0 = t & 63;

  const int gr_l = gm0 + am;
  const int bb_l = gr_l >> 11, s_l = gr_l & 2047;
  const bf16* abase = A + (size_t)bb_l * 2097152 + (size_t)s_l * 64;

  f32x4 acc[4][4];
#pragma unroll
  for (int i = 0; i < 4; i++)
#pragma unroll
    for (int jj = 0; jj < 4; jj++) acc[i][jj] = {0.f, 0.f, 0.f, 0.f};

  const float* wptr = W + (size_t)(w * 8) * 1024 + gn0 + bn0;

  uint4 a0, a1;
  float wb0[8], wb1[8];
  {
    const int c0 = akg * 8;
    const uint4* ap = reinterpret_cast<const uint4*>(abase + (size_t)(c0 >> 6) * 131072 + (c0 & 63));
    a0 = ap[0]; a1 = ap[1];
  }
#pragma unroll
  for (int kk = 0; kk < 8; kk++) { wb0[kk] = wptr[kk * 1024]; wb1[kk] = wptr[kk * 1024 + 64]; }

  for (int kt = 0; kt < 1024; kt += 32) {
    __align__(16) bf16 bb0[8], bb1[8];
#pragma unroll
    for (int i = 0; i < 8; i++) { bb0[i] = __float2bfloat16(wb0[i]); bb1[i] = __float2bfloat16(wb1[i]); }
    __syncthreads();
    *reinterpret_cast<uint4*>(&As[am][swz8(am, akg)])           = a0;
    *reinterpret_cast<uint4*>(&As[am][swz8(am, akg + 1)])       = a1;
    *reinterpret_cast<uint4*>(&Bs[bn0][swz8(bn0, w)])           = *reinterpret_cast<const uint4*>(bb0);
    *reinterpret_cast<uint4*>(&Bs[bn0 + 64][swz8(bn0 + 64, w)]) = *reinterpret_cast<const uint4*>(bb1);
    if (kt + 32 < 1024) {            // prefetch next K-slice
      const int c0 = kt + 32 + akg * 8;
      const uint4* ap = reinterpret_cast<const uint4*>(abase + (size_t)(c0 >> 6) * 131072 + (c0 & 63));
      a0 = ap[0]; a1 = ap[1];
      wptr += 32 * 1024;
#pragma unroll
      for (int kk = 0; kk < 8; kk++) { wb0[kk] = wptr[kk * 1024]; wb1[kk] = wptr[kk * 1024 + 64]; }
    }
    __syncthreads();

    bf16x8 af[4], bfr[4];
#pragma unroll
    for (int mt = 0; mt < 4; mt++) {
      const int r_ = wr * 64 + mt * 16 + l15;
      af[mt] = *reinterpret_cast<const bf16x8*>(&As[r_][swz8(r_, g)]);
    }
#pragma unroll
    for (int nt = 0; nt < 4; nt++) {
      const int r_ = wc * 64 + nt * 16 + l15;
      bfr[nt] = *reinterpret_cast<const bf16x8*>(&Bs[r_][swz8(r_, g)]);
    }
#pragma unroll
    for (int mt = 0; mt < 4; mt++)
#pragma unroll
      for (int nt = 0; nt < 4; nt++)
        acc[mt][nt] = __builtin_amdgcn_mfma_f32_16x16x32_bf16(af[mt], bfr[nt], acc[mt][nt], 0, 0, 0);
  }

#pragma unroll
  for (int nt = 0; nt < 4; nt++) {
    const int gc = gn0 + wc * 64 + nt * 16 + l15;
    const float bvs = bias[gc];
#pragma unroll
    for (int mt = 0; mt < 4; mt++)
#pragma unroll
      for (int r = 0; r < 4; r++) {
        const int gr = gm0 + wr * 64 + mt * 16 + g * 4 + r;
        out[(size_t)gr * 1024 + gc] = acc[mt][nt][r] + bvs;
      }
  }
}

extern "C" void kernel_launch(void* const* d_in, const int* in_sizes, int n_in,
                              void* d_out, int out_size, void* d_ws, size_t ws_size,
                              hipStream_t stream)
{
  const float *x = nullptr, *W_attn = nullptr, *b_attn = nullptr,
              *W_proj = nullptr, *b_proj = nullptr;
  for (int i = 0; i < n_in; i++) {
    switch (in_sizes[i]) {
      case 8388608: x      = (const float*)d_in[i]; break;  // [4,2048,1024]
      case 3145728: W_attn = (const float*)d_in[i]; break;  // [1024,3072]
      case 3072:    b_attn = (const float*)d_in[i]; break;
      case 1048576: W_proj = (const float*)d_in[i]; break;  // [1024,1024]
      case 1024:    b_proj = (const float*)d_in[i]; break;
      default: break;
    }
  }
  if (!x || !W_attn || !b_attn || !W_proj || !b_proj) {
    x = (const float*)d_in[0]; W_attn = (const float*)d_in[1];
    b_attn = (const float*)d_in[2]; W_proj = (const float*)d_in[3];
    b_proj = (const float*)d_in[4];
  }
  float* out = (float*)d_out;        // 8388608 f32 = 32 MiB

  // Memory plan (inputs never written; ws requirement 16 MiB):
  //   Q -> ws[0:16M)  bf16 BHSD, pre-scaled by 0.125 (later overwritten by O)
  //   K -> d_out bytes [0:16M)  bf16 BHSD   } dead before proj's f32 writes
  //   V -> d_out bytes [16M:32M) bf16 BHDS  }  (transposed for MFMA PV)
  const size_t NE = 8388608;         // bf16 elements per 16 MiB tensor
  bf16* qb = (bf16*)d_ws;
  bf16* kb = (bf16*)d_out;
  bf16* vb = kb + NE;

  qkv_f <<<dim3(1536), 256, 0, stream>>>(x, W_attn, b_attn, qb, kb, vb);
  attn_f<<<dim3(1024), 256, 0, stream>>>(qb, kb, vb);
  proj_f<<<dim3(512), 256, 0, stream>>>(qb, W_proj, b_proj, out);
}

// Round 6
// 216.432 us; speedup vs baseline: 10.9880x; 1.0216x over previous
//
#include <hip/hip_runtime.h>
#include <hip/hip_bf16.h>

typedef __hip_bfloat16 bf16;
#define NEG_BIG (-3.0e38f)

// MFMA fragment types (gfx950: v_mfma_f32_16x16x32_bf16 takes <8 x bfloat>)
typedef __bf16 bf16x8 __attribute__((ext_vector_type(8)));
typedef float  f32x4  __attribute__((ext_vector_type(4)));

__device__ inline void load8_f32(const float* p, float* o) {
  float4 a = *reinterpret_cast<const float4*>(p);
  float4 b = *reinterpret_cast<const float4*>(p + 4);
  o[0]=a.x; o[1]=a.y; o[2]=a.z; o[3]=a.w;
  o[4]=b.x; o[5]=b.y; o[6]=b.z; o[7]=b.w;
}

// k-granule XOR swizzle: breaks the 8-way bank conflict of n-row b128 writes
// at row-stride 80B. Element offset of 8-elem granule kg within a row.
__device__ inline int swz8(int row, int kg) { return ((kg ^ ((row >> 3) & 3)) << 3); }

// ---------- Kernel 1: QKV GEMM via MFMA, LDS-double-buffered (1 barrier/iter) ----------
// X[8192,1024]f32 @ W[1024,3072]f32 + b.  128x128 tile, 4 waves 2x2 (64x64/wave).
// Flat grid 1536; decode: xcd=f&7, bm=xcd*8+(j&7), bn=j>>3 (XCD-local X slices).
// Double-buffer safety: iter i writes buf[p], ONE barrier, reads buf[p]; iter
// i+1 writes buf[1-p] concurrently with other waves' buf[p] reads (different
// buffer); re-write of buf[p] at iter i+2 is ordered because every wave's
// buf[p] reads completed before it entered the iter-i+1 barrier (syncthreads
// drains lgkmcnt). Next iteration's global loads issue before the barrier so
// HBM/L2 latency hides under MFMA (T14).
// Q is stored PRE-SCALED by 1/sqrt(HEAD_DIM)=0.125 (folded out of attention).
// Q -> ws bf16 BHSD; K -> d_out[0:16M) bf16 BHSD; V -> d_out[16M:32M) bf16 BHDS.
__global__ __launch_bounds__(256)
void qkv_f(const float* __restrict__ X, const float* __restrict__ W,
           const float* __restrict__ bias,
           bf16* __restrict__ q, bf16* __restrict__ k, bf16* __restrict__ v)
{
  __shared__ __align__(16) bf16 As[2][128][40];   // row = m, 32 k + pad
  __shared__ __align__(16) bf16 Bs[2][128][40];   // row = n, 32 k + pad
  const int t   = threadIdx.x;
  const int f   = blockIdx.x;               // 0..1535
  const int xcd = f & 7, j = f >> 3;        // j 0..191
  const int bm  = xcd * 8 + (j & 7);        // 0..63
  const int bn  = j >> 3;                   // 0..23
  const int gm0 = bm * 128, gn0 = bn * 128;
  const int w    = t >> 6, lane = t & 63;
  const int g    = lane >> 4, l15 = lane & 15;
  const int wr   = w >> 1, wc = w & 1;

  const int am  = t >> 1, akg = (t & 1) * 2;   // A staging: row am, granules akg,akg+1
  const int bn0 = t & 63;                       // B staging: rows bn0,bn0+64, granule w

  f32x4 acc[4][4];
#pragma unroll
  for (int i = 0; i < 4; i++)
#pragma unroll
    for (int jj = 0; jj < 4; jj++) acc[i][jj] = {0.f, 0.f, 0.f, 0.f};

  const float* aptr = X + (size_t)(gm0 + am) * 1024 + akg * 8;
  const float* wptr = W + (size_t)(w * 8) * 3072 + gn0 + bn0;

  float a32[16], wb0[8], wb1[8];
  load8_f32(aptr, a32);
  load8_f32(aptr + 8, a32 + 8);
#pragma unroll
  for (int kk = 0; kk < 8; kk++) { wb0[kk] = wptr[kk * 3072]; wb1[kk] = wptr[kk * 3072 + 64]; }

  for (int kt = 0; kt < 1024; kt += 32) {
    const int p = (kt >> 5) & 1;
    __align__(16) bf16 ab[16], bb0[8], bb1[8];
#pragma unroll
    for (int i = 0; i < 16; i++) ab[i] = __float2bfloat16(a32[i]);
#pragma unroll
    for (int i = 0; i < 8; i++) { bb0[i] = __float2bfloat16(wb0[i]); bb1[i] = __float2bfloat16(wb1[i]); }
    *reinterpret_cast<uint4*>(&As[p][am][swz8(am, akg)])           = reinterpret_cast<const uint4*>(ab)[0];
    *reinterpret_cast<uint4*>(&As[p][am][swz8(am, akg + 1)])       = reinterpret_cast<const uint4*>(ab)[1];
    *reinterpret_cast<uint4*>(&Bs[p][bn0][swz8(bn0, w)])           = *reinterpret_cast<const uint4*>(bb0);
    *reinterpret_cast<uint4*>(&Bs[p][bn0 + 64][swz8(bn0 + 64, w)]) = *reinterpret_cast<const uint4*>(bb1);
    if (kt + 32 < 1024) {            // prefetch next K-slice (hides under MFMA)
      aptr += 32; wptr += 32 * 3072;
      load8_f32(aptr, a32);
      load8_f32(aptr + 8, a32 + 8);
#pragma unroll
      for (int kk = 0; kk < 8; kk++) { wb0[kk] = wptr[kk * 3072]; wb1[kk] = wptr[kk * 3072 + 64]; }
    }
    __syncthreads();                 // single barrier: buf[p] writes visible

    bf16x8 af[4], bfr[4];
#pragma unroll
    for (int mt = 0; mt < 4; mt++) {
      const int r_ = wr * 64 + mt * 16 + l15;
      af[mt] = *reinterpret_cast<const bf16x8*>(&As[p][r_][swz8(r_, g)]);
    }
#pragma unroll
    for (int nt = 0; nt < 4; nt++) {
      const int r_ = wc * 64 + nt * 16 + l15;
      bfr[nt] = *reinterpret_cast<const bf16x8*>(&Bs[p][r_][swz8(r_, g)]);
    }
#pragma unroll
    for (int mt = 0; mt < 4; mt++)
#pragma unroll
      for (int nt = 0; nt < 4; nt++)
        acc[mt][nt] = __builtin_amdgcn_mfma_f32_16x16x32_bf16(af[mt], bfr[nt], acc[mt][nt], 0, 0, 0);
  }

  // Epilogue: C layout row = g*4+r, col = l15. Scatter to Q/K/V (V transposed).
#pragma unroll
  for (int nt = 0; nt < 4; nt++) {
    const int gc  = gn0 + wc * 64 + nt * 16 + l15;   // never crosses Q/K/V or head boundary
    const float bvs = bias[gc];
    const int which = gc >> 10;
    const int cc = gc & 1023;
    const int hh = cc >> 6, d = cc & 63;
    bf16* dst = (which == 0) ? q : ((which == 1) ? k : v);
#pragma unroll
    for (int mt = 0; mt < 4; mt++)
#pragma unroll
      for (int r = 0; r < 4; r++) {
        const int gr = gm0 + wr * 64 + mt * 16 + g * 4 + r;
        const int bb = gr >> 11, s = gr & 2047;
        float val = acc[mt][nt][r] + bvs;
        if (which == 0) val *= 0.125f;   // fold softmax scale into Q
        if (which == 2)
          dst[((size_t)(bb * 16 + hh) * 64 + d) * 2048 + s] = __float2bfloat16(val);
        else
          dst[((size_t)(bb * 16 + hh) * 2048 + s) * 64 + d] = __float2bfloat16(val);
      }
  }
}

// ---------- Kernel 2: causal flash attention via MFMA, swapped QK^T ----------
// Triangular-paired + XCD-local grid: 1024 blocks (all co-resident, 4/CU).
// Block = (hb pair, qt0); processes q-tile 31-qt0 then qt0 => exactly 34
// KV-tiles per block (perfect balance). Decode puts the 16 blocks of each
// (b,h) on ONE XCD (hb = (f&7) + 8*(f>>7)) so that XCD's L2 working set is
// 8 heads x 512KB = 4MB: K/V re-reads become L2 hits instead of HBM/L3.
// Per-wave body: swapped mfma(K,Q), in-lane softmax, reg prefetch.
// (LDS kept single-buffered: 27.6KB x 4 blocks/CU preserves full residency.)
__global__ __launch_bounds__(256)
void attn_f(bf16* __restrict__ qo, const bf16* __restrict__ k, const bf16* __restrict__ v)
{
  __shared__ __align__(16) bf16 Ks[64][72];     // K tile, row = k, col = d
  __shared__ __align__(16) bf16 Vt[64][72];     // V tile, row = d, col = k
  __shared__ __align__(16) bf16 Ps[4][16][72];  // per-wave P, row = q, col = k

  const int t    = threadIdx.x;
  const int f    = blockIdx.x;            // 0..1023
  const int xcd  = f & 7;
  const int j    = f >> 3;                // 0..127
  const int hb   = xcd + 8 * (j >> 4);    // 0..63, fixed per XCD
  const int qt0  = j & 15;                // 0..15
  const int b    = hb >> 4, h = hb & 15;
  const size_t basebh = (size_t)(b * 16 + h) * 2048 * 64;

  const int w    = t >> 6;
  const int lane = t & 63;
  const int g    = lane >> 4;
  const int l15  = lane & 15;

  const int sr = t >> 3;          // staging row 0..31
  const int sc = (t & 7) * 8;     // staging col (elements)
  const bf16* kbase = k + basebh;
  const bf16* vbase = v + basebh;

#pragma unroll 1
  for (int pass = 0; pass < 2; ++pass) {
    const int qt = pass ? qt0 : (31 - qt0);
    const int qb = qt * 64 + w * 16;

    // Q B-fragments for this pass (operand order in mfma is swapped)
    const bf16* qrow = qo + basebh + (size_t)(qb + l15) * 64;
    bf16x8 qf0 = *reinterpret_cast<const bf16x8*>(qrow + g * 8);
    bf16x8 qf1 = *reinterpret_cast<const bf16x8*>(qrow + 32 + g * 8);

    f32x4 acc[4] = {{0,0,0,0},{0,0,0,0},{0,0,0,0},{0,0,0,0}};
    float m_run = NEG_BIG, l_run = 0.f;   // canonical per-lane q = qb + l15

    uint4 kreg0, kreg1, vreg0, vreg1;
    {
      kreg0 = *reinterpret_cast<const uint4*>(kbase + (size_t)(sr) * 64 + sc);
      kreg1 = *reinterpret_cast<const uint4*>(kbase + (size_t)(32 + sr) * 64 + sc);
      vreg0 = *reinterpret_cast<const uint4*>(vbase + (size_t)sr * 2048 + sc);
      vreg1 = *reinterpret_cast<const uint4*>(vbase + (size_t)(32 + sr) * 2048 + sc);
    }

    for (int ct = 0; ct <= qt; ++ct) {
      const int kv0 = ct * 64;
      __syncthreads();              // all waves done reading previous tile
      *reinterpret_cast<uint4*>(&Ks[sr][sc])      = kreg0;
      *reinterpret_cast<uint4*>(&Ks[32 + sr][sc]) = kreg1;
      *reinterpret_cast<uint4*>(&Vt[sr][sc])      = vreg0;
      *reinterpret_cast<uint4*>(&Vt[32 + sr][sc]) = vreg1;
      if (ct < qt) {                // prefetch next tile (hides under compute)
        const int nv0 = kv0 + 64;
        kreg0 = *reinterpret_cast<const uint4*>(kbase + (size_t)(nv0 + sr) * 64 + sc);
        kreg1 = *reinterpret_cast<const uint4*>(kbase + (size_t)(nv0 + 32 + sr) * 64 + sc);
        vreg0 = *reinterpret_cast<const uint4*>(vbase + (size_t)sr * 2048 + nv0 + sc);
        vreg1 = *reinterpret_cast<const uint4*>(vbase + (size_t)(32 + sr) * 2048 + nv0 + sc);
      }
      __syncthreads();

      // ---- S^T tile: st[kt][r] = S[k = kv0+kt*16+g*4+r][q = qb+l15] ----
      f32x4 st[4];
#pragma unroll
      for (int kt = 0; kt < 4; ++kt) {
        const int kr = kt * 16 + l15;
        bf16x8 kf0 = *reinterpret_cast<const bf16x8*>(&Ks[kr][g * 8]);
        bf16x8 kf1 = *reinterpret_cast<const bf16x8*>(&Ks[kr][32 + g * 8]);
        f32x4 c4 = {0,0,0,0};
        c4 = __builtin_amdgcn_mfma_f32_16x16x32_bf16(kf0, qf0, c4, 0, 0, 0);
        c4 = __builtin_amdgcn_mfma_f32_16x16x32_bf16(kf1, qf1, c4, 0, 0, 0);
        st[kt] = c4;
      }
      if (ct == qt) {               // causal mask, diagonal tile only
        const int qg = qb + l15;
#pragma unroll
        for (int kt = 0; kt < 4; ++kt)
#pragma unroll
          for (int r = 0; r < 4; ++r)
            if (kv0 + kt * 16 + g * 4 + r > qg) st[kt][r] = NEG_BIG;
      }

      // ---- online softmax: in-lane reduce + cross-group (masks 16,32) ----
      float mc = NEG_BIG;
#pragma unroll
      for (int kt = 0; kt < 4; ++kt)
#pragma unroll
        for (int r = 0; r < 4; ++r) mc = fmaxf(mc, st[kt][r]);
      mc = fmaxf(mc, __shfl_xor(mc, 16));
      mc = fmaxf(mc, __shfl_xor(mc, 32));
      const float mn = fmaxf(m_run, mc);
      const float alpha = __expf(m_run - mn);
      m_run = mn;
      float ps = 0.f;
#pragma unroll
      for (int kt = 0; kt < 4; ++kt)
#pragma unroll
        for (int r = 0; r < 4; ++r) {
          const float pv = __expf(st[kt][r] - mn);
          st[kt][r] = pv;
          ps += pv;
        }
      ps += __shfl_xor(ps, 16);
      ps += __shfl_xor(ps, 32);
      l_run = l_run * alpha + ps;

      // redistribute alpha (held per q=l15) to accumulator layout (q=g*4+r)
#pragma unroll
      for (int r = 0; r < 4; ++r) {
        const float ar = __shfl(alpha, g * 4 + r, 64);
#pragma unroll
        for (int dt = 0; dt < 4; ++dt) acc[dt][r] *= ar;
      }

      // ---- P -> per-wave LDS, packed b64 (4 bf16 per write) ----
#pragma unroll
      for (int kt = 0; kt < 4; ++kt) {
        union { bf16 hh[4]; uint2 u; } pk;
        pk.hh[0] = __float2bfloat16(st[kt][0]);
        pk.hh[1] = __float2bfloat16(st[kt][1]);
        pk.hh[2] = __float2bfloat16(st[kt][2]);
        pk.hh[3] = __float2bfloat16(st[kt][3]);
        *reinterpret_cast<uint2*>(&Ps[w][l15][kt * 16 + g * 4]) = pk.u;
      }
      __builtin_amdgcn_sched_barrier(0);

      // ---- O += P V  (A = P rows=q, B = V^T rows=d) ----
#pragma unroll
      for (int kc = 0; kc < 2; ++kc) {
        bf16x8 pf = *reinterpret_cast<const bf16x8*>(&Ps[w][l15][kc * 32 + g * 8]);
#pragma unroll
        for (int dt = 0; dt < 4; ++dt) {
          bf16x8 vf = *reinterpret_cast<const bf16x8*>(&Vt[dt * 16 + l15][kc * 32 + g * 8]);
          acc[dt] = __builtin_amdgcn_mfma_f32_16x16x32_bf16(pf, vf, acc[dt], 0, 0, 0);
        }
      }
    }

    // ---- epilogue: O = acc / l, in-place over this pass's Q slab ----
    const float linv = 1.f / l_run;            // for q = qb + l15
    float inv[4];
#pragma unroll
    for (int r = 0; r < 4; ++r) inv[r] = __shfl(linv, g * 4 + r, 64);
    bf16* op = qo + basebh;
#pragma unroll
    for (int dt = 0; dt < 4; ++dt)
#pragma unroll
      for (int r = 0; r < 4; ++r)
        op[(size_t)(qb + g * 4 + r) * 64 + dt * 16 + l15] =
            __float2bfloat16(acc[dt][r] * inv[r]);
  }
}

// ---------- Kernel 3: projection via MFMA, LDS-double-buffered (1 barrier/iter) ----------
// A = O bf16 BHSD (ws), already bf16 -> raw b128 staging (no cvt).
// W_proj f32 -> bf16 staged transposed, out f32 [8192,1024].
__global__ __launch_bounds__(256)
void proj_f(const bf16* __restrict__ A, const float* __restrict__ W,
            const float* __restrict__ bias, float* __restrict__ out)
{
  __shared__ __align__(16) bf16 As[2][128][40];
  __shared__ __align__(16) bf16 Bs[2][128][40];
  const int t   = threadIdx.x;
  const int f   = blockIdx.x;               // 0..511
  const int xcd = f & 7, j = f >> 3;        // j 0..63
  const int bm  = xcd * 8 + (j & 7);        // 0..63
  const int bn  = j >> 3;                   // 0..7
  const int gm0 = bm * 128, gn0 = bn * 128;
  const int w    = t >> 6, lane = t & 63;
  const int g    = lane >> 4, l15 = lane & 15;
  const int wr   = w >> 1, wc = w & 1;

  const int am  = t >> 1, akg = (t & 1) * 2;
  const int bn0 = t & 63;

  const int gr_l = gm0 + am;
  const int bb_l = gr_l >> 11, s_l = gr_l & 2047;
  const bf16* abase = A + (size_t)bb_l * 2097152 + (size_t)s_l * 64;

  f32x4 acc[4][4];
#pragma unroll
  for (int i = 0; i < 4; i++)
#pragma unroll
    for (int jj = 0; jj < 4; jj++) acc[i][jj] = {0.f, 0.f, 0.f, 0.f};

  const float* wptr = W + (size_t)(w * 8) * 1024 + gn0 + bn0;

  uint4 a0, a1;
  float wb0[8], wb1[8];
  {
    const int c0 = akg * 8;
    const uint4* ap = reinterpret_cast<const uint4*>(abase + (size_t)(c0 >> 6) * 131072 + (c0 & 63));
    a0 = ap[0]; a1 = ap[1];
  }
#pragma unroll
  for (int kk = 0; kk < 8; kk++) { wb0[kk] = wptr[kk * 1024]; wb1[kk] = wptr[kk * 1024 + 64]; }

  for (int kt = 0; kt < 1024; kt += 32) {
    const int p = (kt >> 5) & 1;
    __align__(16) bf16 bb0[8], bb1[8];
#pragma unroll
    for (int i = 0; i < 8; i++) { bb0[i] = __float2bfloat16(wb0[i]); bb1[i] = __float2bfloat16(wb1[i]); }
    *reinterpret_cast<uint4*>(&As[p][am][swz8(am, akg)])           = a0;
    *reinterpret_cast<uint4*>(&As[p][am][swz8(am, akg + 1)])       = a1;
    *reinterpret_cast<uint4*>(&Bs[p][bn0][swz8(bn0, w)])           = *reinterpret_cast<const uint4*>(bb0);
    *reinterpret_cast<uint4*>(&Bs[p][bn0 + 64][swz8(bn0 + 64, w)]) = *reinterpret_cast<const uint4*>(bb1);
    if (kt + 32 < 1024) {            // prefetch next K-slice
      const int c0 = kt + 32 + akg * 8;
      const uint4* ap = reinterpret_cast<const uint4*>(abase + (size_t)(c0 >> 6) * 131072 + (c0 & 63));
      a0 = ap[0]; a1 = ap[1];
      wptr += 32 * 1024;
#pragma unroll
      for (int kk = 0; kk < 8; kk++) { wb0[kk] = wptr[kk * 1024]; wb1[kk] = wptr[kk * 1024 + 64]; }
    }
    __syncthreads();                 // single barrier: buf[p] writes visible

    bf16x8 af[4], bfr[4];
#pragma unroll
    for (int mt = 0; mt < 4; mt++) {
      const int r_ = wr * 64 + mt * 16 + l15;
      af[mt] = *reinterpret_cast<const bf16x8*>(&As[p][r_][swz8(r_, g)]);
    }
#pragma unroll
    for (int nt = 0; nt < 4; nt++) {
      const int r_ = wc * 64 + nt * 16 + l15;
      bfr[nt] = *reinterpret_cast<const bf16x8*>(&Bs[p][r_][swz8(r_, g)]);
    }
#pragma unroll
    for (int mt = 0; mt < 4; mt++)
#pragma unroll
      for (int nt = 0; nt < 4; nt++)
        acc[mt][nt] = __builtin_amdgcn_mfma_f32_16x16x32_bf16(af[mt], bfr[nt], acc[mt][nt], 0, 0, 0);
  }

#pragma unroll
  for (int nt = 0; nt < 4; nt++) {
    const int gc = gn0 + wc * 64 + nt * 16 + l15;
    const float bvs = bias[gc];
#pragma unroll
    for (int mt = 0; mt < 4; mt++)
#pragma unroll
      for (int r = 0; r < 4; r++) {
        const int gr = gm0 + wr * 64 + mt * 16 + g * 4 + r;
        out[(size_t)gr * 1024 + gc] = acc[mt][nt][r] + bvs;
      }
  }
}

extern "C" void kernel_launch(void* const* d_in, const int* in_sizes, int n_in,
                              void* d_out, int out_size, void* d_ws, size_t ws_size,
                              hipStream_t stream)
{
  const float *x = nullptr, *W_attn = nullptr, *b_attn = nullptr,
              *W_proj = nullptr, *b_proj = nullptr;
  for (int i = 0; i < n_in; i++) {
    switch (in_sizes[i]) {
      case 8388608: x      = (const float*)d_in[i]; break;  // [4,2048,1024]
      case 3145728: W_attn = (const float*)d_in[i]; break;  // [1024,3072]
      case 3072:    b_attn = (const float*)d_in[i]; break;
      case 1048576: W_proj = (const float*)d_in[i]; break;  // [1024,1024]
      case 1024:    b_proj = (const float*)d_in[i]; break;
      default: break;
    }
  }
  if (!x || !W_attn || !b_attn || !W_proj || !b_proj) {
    x = (const float*)d_in[0]; W_attn = (const float*)d_in[1];
    b_attn = (const float*)d_in[2]; W_proj = (const float*)d_in[3];
    b_proj = (const float*)d_in[4];
  }
  float* out = (float*)d_out;        // 8388608 f32 = 32 MiB

  // Memory plan (inputs never written; ws requirement 16 MiB):
  //   Q -> ws[0:16M)  bf16 BHSD, pre-scaled by 0.125 (later overwritten by O)
  //   K -> d_out bytes [0:16M)  bf16 BHSD   } dead before proj's f32 writes
  //   V -> d_out bytes [16M:32M) bf16 BHDS  }  (transposed for MFMA PV)
  const size_t NE = 8388608;         // bf16 elements per 16 MiB tensor
  bf16* qb = (bf16*)d_ws;
  bf16* kb = (bf16*)d_out;
  bf16* vb = kb + NE;

  qkv_f <<<dim3(1536), 256, 0, stream>>>(x, W_attn, b_attn, qb, kb, vb);
  attn_f<<<dim3(1024), 256, 0, stream>>>(qb, kb, vb);
  proj_f<<<dim3(512), 256, 0, stream>>>(qb, W_proj, b_proj, out);
}

// Round 7
// 212.956 us; speedup vs baseline: 11.1674x; 1.0163x over previous
//
#include <hip/hip_runtime.h>
#include <hip/hip_bf16.h>

typedef __hip_bfloat16 bf16;
#define NEG_BIG (-3.0e38f)

// MFMA fragment types (gfx950: v_mfma_f32_16x16x32_bf16 takes <8 x bfloat>)
typedef __bf16 bf16x8 __attribute__((ext_vector_type(8)));
typedef float  f32x4  __attribute__((ext_vector_type(4)));

__device__ inline void load8_f32(const float* p, float* o) {
  float4 a = *reinterpret_cast<const float4*>(p);
  float4 b = *reinterpret_cast<const float4*>(p + 4);
  o[0]=a.x; o[1]=a.y; o[2]=a.z; o[3]=a.w;
  o[4]=b.x; o[5]=b.y; o[6]=b.z; o[7]=b.w;
}

// k-granule XOR swizzle: breaks the 8-way bank conflict of n-row b128 writes
// at row-stride 80B. Element offset of 8-elem granule kg within a row.
// Rows r and r+8/16/24 share banks at stride 80B; XOR of (r>>3)&3 rotates
// their granules to distinct 16B slots; r vs r+32 is 2-way (free, m136).
__device__ inline int swz8(int row, int kg) { return ((kg ^ ((row >> 3) & 3)) << 3); }

// ---------- Kernel 1: QKV GEMM via MFMA, 8-wave split, dbuf (1 barrier/iter) ----------
// X[8192,1024]f32 @ W[1024,3072]f32 + b.  128x128 tile, 8 waves 2x4 (64x32/wave).
// 512 threads: per-thread staging = 2 dwordx4 (A) + 8 dword (B) + 16 cvts +
// 2 b128 LDS writes -> half the per-wave serial chain of the 4-wave version,
// and ~90 regs/wave -> 2 blocks (16 waves)/CU resident for latency hiding.
// Flat grid 1536; decode: xcd=f&7, bm=xcd*8+(j&7), bn=j>>3 (XCD-local X slices).
// Double-buffer: iter i writes buf[p], ONE barrier, reads buf[p]; re-write of
// buf[p] at i+2 ordered by the i+1 barrier (syncthreads drains lgkmcnt).
// Q is stored PRE-SCALED by 1/sqrt(HEAD_DIM)=0.125 (folded out of attention).
// Q -> ws bf16 BHSD; K -> d_out[0:16M) bf16 BHSD; V -> d_out[16M:32M) bf16 BHDS.
__global__ __launch_bounds__(512)
void qkv_f(const float* __restrict__ X, const float* __restrict__ W,
           const float* __restrict__ bias,
           bf16* __restrict__ q, bf16* __restrict__ k, bf16* __restrict__ v)
{
  __shared__ __align__(16) bf16 As[2][128][40];   // row = m, 32 k + pad
  __shared__ __align__(16) bf16 Bs[2][128][40];   // row = n, 32 k + pad
  const int t   = threadIdx.x;
  const int f   = blockIdx.x;               // 0..1535
  const int xcd = f & 7, j = f >> 3;        // j 0..191
  const int bm  = xcd * 8 + (j & 7);        // 0..63
  const int bn  = j >> 3;                   // 0..23
  const int gm0 = bm * 128, gn0 = bn * 128;
  const int w    = t >> 6, lane = t & 63;
  const int g    = lane >> 4, l15 = lane & 15;
  const int wr   = w >> 2, wc = w & 3;      // 2x4 wave grid -> wave tile 64x32

  const int am  = t >> 2, akg = t & 3;      // A staging: row am, granule akg
  const int bnr = t & 127, bkg = t >> 7;    // B staging: row bnr, granule bkg

  f32x4 acc[4][2];
#pragma unroll
  for (int i = 0; i < 4; i++)
#pragma unroll
    for (int jj = 0; jj < 2; jj++) acc[i][jj] = {0.f, 0.f, 0.f, 0.f};

  const float* aptr = X + (size_t)(gm0 + am) * 1024 + akg * 8;
  const float* wptr = W + (size_t)(bkg * 8) * 3072 + gn0 + bnr;

  float a32[8], wb[8];
  load8_f32(aptr, a32);
#pragma unroll
  for (int kk = 0; kk < 8; kk++) wb[kk] = wptr[kk * 3072];

  for (int kt = 0; kt < 1024; kt += 32) {
    const int p = (kt >> 5) & 1;
    __align__(16) bf16 ab[8], bb[8];
#pragma unroll
    for (int i = 0; i < 8; i++) { ab[i] = __float2bfloat16(a32[i]); bb[i] = __float2bfloat16(wb[i]); }
    *reinterpret_cast<uint4*>(&As[p][am][swz8(am, akg)])   = *reinterpret_cast<const uint4*>(ab);
    *reinterpret_cast<uint4*>(&Bs[p][bnr][swz8(bnr, bkg)]) = *reinterpret_cast<const uint4*>(bb);
    if (kt + 32 < 1024) {            // prefetch next K-slice (hides under MFMA)
      aptr += 32; wptr += 32 * 3072;
      load8_f32(aptr, a32);
#pragma unroll
      for (int kk = 0; kk < 8; kk++) wb[kk] = wptr[kk * 3072];
    }
    __syncthreads();                 // single barrier: buf[p] writes visible

    bf16x8 af[4], bfr[2];
#pragma unroll
    for (int mt = 0; mt < 4; mt++) {
      const int r_ = wr * 64 + mt * 16 + l15;
      af[mt] = *reinterpret_cast<const bf16x8*>(&As[p][r_][swz8(r_, g)]);
    }
#pragma unroll
    for (int nt = 0; nt < 2; nt++) {
      const int r_ = wc * 32 + nt * 16 + l15;
      bfr[nt] = *reinterpret_cast<const bf16x8*>(&Bs[p][r_][swz8(r_, g)]);
    }
#pragma unroll
    for (int mt = 0; mt < 4; mt++)
#pragma unroll
      for (int nt = 0; nt < 2; nt++)
        acc[mt][nt] = __builtin_amdgcn_mfma_f32_16x16x32_bf16(af[mt], bfr[nt], acc[mt][nt], 0, 0, 0);
  }

  // Epilogue: C layout row = g*4+r, col = l15. Scatter to Q/K/V (V transposed).
#pragma unroll
  for (int nt = 0; nt < 2; nt++) {
    const int gc  = gn0 + wc * 32 + nt * 16 + l15;   // never crosses Q/K/V or head boundary
    const float bvs = bias[gc];
    const int which = gc >> 10;
    const int cc = gc & 1023;
    const int hh = cc >> 6, d = cc & 63;
    bf16* dst = (which == 0) ? q : ((which == 1) ? k : v);
#pragma unroll
    for (int mt = 0; mt < 4; mt++)
#pragma unroll
      for (int r = 0; r < 4; r++) {
        const int gr = gm0 + wr * 64 + mt * 16 + g * 4 + r;
        const int bb = gr >> 11, s = gr & 2047;
        float val = acc[mt][nt][r] + bvs;
        if (which == 0) val *= 0.125f;   // fold softmax scale into Q
        if (which == 2)
          dst[((size_t)(bb * 16 + hh) * 64 + d) * 2048 + s] = __float2bfloat16(val);
        else
          dst[((size_t)(bb * 16 + hh) * 2048 + s) * 64 + d] = __float2bfloat16(val);
      }
  }
}

// ---------- Kernel 2: causal flash attention via MFMA, swapped QK^T ----------
// Triangular-paired + XCD-local grid: 1024 blocks (all co-resident, 4/CU).
// Block = (hb pair, qt0); processes q-tile 31-qt0 then qt0 => exactly 34
// KV-tiles per block (perfect balance). Decode puts the 16 blocks of each
// (b,h) on ONE XCD (hb = (f&7) + 8*(f>>7)) so that XCD's L2 working set is
// 8 heads x 512KB = 4MB: K/V re-reads become L2 hits instead of HBM/L3.
// Per-wave body: swapped mfma(K,Q), in-lane softmax, reg prefetch.
__global__ __launch_bounds__(256)
void attn_f(bf16* __restrict__ qo, const bf16* __restrict__ k, const bf16* __restrict__ v)
{
  __shared__ __align__(16) bf16 Ks[64][72];     // K tile, row = k, col = d
  __shared__ __align__(16) bf16 Vt[64][72];     // V tile, row = d, col = k
  __shared__ __align__(16) bf16 Ps[4][16][72];  // per-wave P, row = q, col = k

  const int t    = threadIdx.x;
  const int f    = blockIdx.x;            // 0..1023
  const int xcd  = f & 7;
  const int j    = f >> 3;                // 0..127
  const int hb   = xcd + 8 * (j >> 4);    // 0..63, fixed per XCD
  const int qt0  = j & 15;                // 0..15
  const int b    = hb >> 4, h = hb & 15;
  const size_t basebh = (size_t)(b * 16 + h) * 2048 * 64;

  const int w    = t >> 6;
  const int lane = t & 63;
  const int g    = lane >> 4;
  const int l15  = lane & 15;

  const int sr = t >> 3;          // staging row 0..31
  const int sc = (t & 7) * 8;     // staging col (elements)
  const bf16* kbase = k + basebh;
  const bf16* vbase = v + basebh;

#pragma unroll 1
  for (int pass = 0; pass < 2; ++pass) {
    const int qt = pass ? qt0 : (31 - qt0);
    const int qb = qt * 64 + w * 16;

    // Q B-fragments for this pass (operand order in mfma is swapped)
    const bf16* qrow = qo + basebh + (size_t)(qb + l15) * 64;
    bf16x8 qf0 = *reinterpret_cast<const bf16x8*>(qrow + g * 8);
    bf16x8 qf1 = *reinterpret_cast<const bf16x8*>(qrow + 32 + g * 8);

    f32x4 acc[4] = {{0,0,0,0},{0,0,0,0},{0,0,0,0},{0,0,0,0}};
    float m_run = NEG_BIG, l_run = 0.f;   // canonical per-lane q = qb + l15

    uint4 kreg0, kreg1, vreg0, vreg1;
    {
      kreg0 = *reinterpret_cast<const uint4*>(kbase + (size_t)(sr) * 64 + sc);
      kreg1 = *reinterpret_cast<const uint4*>(kbase + (size_t)(32 + sr) * 64 + sc);
      vreg0 = *reinterpret_cast<const uint4*>(vbase + (size_t)sr * 2048 + sc);
      vreg1 = *reinterpret_cast<const uint4*>(vbase + (size_t)(32 + sr) * 2048 + sc);
    }

    for (int ct = 0; ct <= qt; ++ct) {
      const int kv0 = ct * 64;
      __syncthreads();              // all waves done reading previous tile
      *reinterpret_cast<uint4*>(&Ks[sr][sc])      = kreg0;
      *reinterpret_cast<uint4*>(&Ks[32 + sr][sc]) = kreg1;
      *reinterpret_cast<uint4*>(&Vt[sr][sc])      = vreg0;
      *reinterpret_cast<uint4*>(&Vt[32 + sr][sc]) = vreg1;
      if (ct < qt) {                // prefetch next tile (hides under compute)
        const int nv0 = kv0 + 64;
        kreg0 = *reinterpret_cast<const uint4*>(kbase + (size_t)(nv0 + sr) * 64 + sc);
        kreg1 = *reinterpret_cast<const uint4*>(kbase + (size_t)(nv0 + 32 + sr) * 64 + sc);
        vreg0 = *reinterpret_cast<const uint4*>(vbase + (size_t)sr * 2048 + nv0 + sc);
        vreg1 = *reinterpret_cast<const uint4*>(vbase + (size_t)(32 + sr) * 2048 + nv0 + sc);
      }
      __syncthreads();

      // ---- S^T tile: st[kt][r] = S[k = kv0+kt*16+g*4+r][q = qb+l15] ----
      f32x4 st[4];
#pragma unroll
      for (int kt = 0; kt < 4; ++kt) {
        const int kr = kt * 16 + l15;
        bf16x8 kf0 = *reinterpret_cast<const bf16x8*>(&Ks[kr][g * 8]);
        bf16x8 kf1 = *reinterpret_cast<const bf16x8*>(&Ks[kr][32 + g * 8]);
        f32x4 c4 = {0,0,0,0};
        c4 = __builtin_amdgcn_mfma_f32_16x16x32_bf16(kf0, qf0, c4, 0, 0, 0);
        c4 = __builtin_amdgcn_mfma_f32_16x16x32_bf16(kf1, qf1, c4, 0, 0, 0);
        st[kt] = c4;
      }
      if (ct == qt) {               // causal mask, diagonal tile only
        const int qg = qb + l15;
#pragma unroll
        for (int kt = 0; kt < 4; ++kt)
#pragma unroll
          for (int r = 0; r < 4; ++r)
            if (kv0 + kt * 16 + g * 4 + r > qg) st[kt][r] = NEG_BIG;
      }

      // ---- online softmax: in-lane reduce + cross-group (masks 16,32) ----
      float mc = NEG_BIG;
#pragma unroll
      for (int kt = 0; kt < 4; ++kt)
#pragma unroll
        for (int r = 0; r < 4; ++r) mc = fmaxf(mc, st[kt][r]);
      mc = fmaxf(mc, __shfl_xor(mc, 16));
      mc = fmaxf(mc, __shfl_xor(mc, 32));
      const float mn = fmaxf(m_run, mc);
      const float alpha = __expf(m_run - mn);
      m_run = mn;
      float ps = 0.f;
#pragma unroll
      for (int kt = 0; kt < 4; ++kt)
#pragma unroll
        for (int r = 0; r < 4; ++r) {
          const float pv = __expf(st[kt][r] - mn);
          st[kt][r] = pv;
          ps += pv;
        }
      ps += __shfl_xor(ps, 16);
      ps += __shfl_xor(ps, 32);
      l_run = l_run * alpha + ps;

      // redistribute alpha (held per q=l15) to accumulator layout (q=g*4+r)
#pragma unroll
      for (int r = 0; r < 4; ++r) {
        const float ar = __shfl(alpha, g * 4 + r, 64);
#pragma unroll
        for (int dt = 0; dt < 4; ++dt) acc[dt][r] *= ar;
      }

      // ---- P -> per-wave LDS, packed b64 (4 bf16 per write) ----
#pragma unroll
      for (int kt = 0; kt < 4; ++kt) {
        union { bf16 hh[4]; uint2 u; } pk;
        pk.hh[0] = __float2bfloat16(st[kt][0]);
        pk.hh[1] = __float2bfloat16(st[kt][1]);
        pk.hh[2] = __float2bfloat16(st[kt][2]);
        pk.hh[3] = __float2bfloat16(st[kt][3]);
        *reinterpret_cast<uint2*>(&Ps[w][l15][kt * 16 + g * 4]) = pk.u;
      }
      __builtin_amdgcn_sched_barrier(0);

      // ---- O += P V  (A = P rows=q, B = V^T rows=d) ----
#pragma unroll
      for (int kc = 0; kc < 2; ++kc) {
        bf16x8 pf = *reinterpret_cast<const bf16x8*>(&Ps[w][l15][kc * 32 + g * 8]);
#pragma unroll
        for (int dt = 0; dt < 4; ++dt) {
          bf16x8 vf = *reinterpret_cast<const bf16x8*>(&Vt[dt * 16 + l15][kc * 32 + g * 8]);
          acc[dt] = __builtin_amdgcn_mfma_f32_16x16x32_bf16(pf, vf, acc[dt], 0, 0, 0);
        }
      }
    }

    // ---- epilogue: O = acc / l, in-place over this pass's Q slab ----
    const float linv = 1.f / l_run;            // for q = qb + l15
    float inv[4];
#pragma unroll
    for (int r = 0; r < 4; ++r) inv[r] = __shfl(linv, g * 4 + r, 64);
    bf16* op = qo + basebh;
#pragma unroll
    for (int dt = 0; dt < 4; ++dt)
#pragma unroll
      for (int r = 0; r < 4; ++r)
        op[(size_t)(qb + g * 4 + r) * 64 + dt * 16 + l15] =
            __float2bfloat16(acc[dt][r] * inv[r]);
  }
}

// ---------- Kernel 3: projection via MFMA, 8-wave split, dbuf (1 barrier/iter) ----------
// A = O bf16 BHSD (ws), already bf16 -> raw b128 staging (no cvt).
// W_proj f32 -> bf16 staged transposed, out f32 [8192,1024].
__global__ __launch_bounds__(512)
void proj_f(const bf16* __restrict__ A, const float* __restrict__ W,
            const float* __restrict__ bias, float* __restrict__ out)
{
  __shared__ __align__(16) bf16 As[2][128][40];
  __shared__ __align__(16) bf16 Bs[2][128][40];
  const int t   = threadIdx.x;
  const int f   = blockIdx.x;               // 0..511
  const int xcd = f & 7, j = f >> 3;        // j 0..63
  const int bm  = xcd * 8 + (j & 7);        // 0..63
  const int bn  = j >> 3;                   // 0..7
  const int gm0 = bm * 128, gn0 = bn * 128;
  const int w    = t >> 6, lane = t & 63;
  const int g    = lane >> 4, l15 = lane & 15;
  const int wr   = w >> 2, wc = w & 3;      // 2x4 wave grid -> wave tile 64x32

  const int am  = t >> 2, akg = t & 3;
  const int bnr = t & 127, bkg = t >> 7;

  const int gr_l = gm0 + am;
  const int bb_l = gr_l >> 11, s_l = gr_l & 2047;
  const bf16* abase = A + (size_t)bb_l * 2097152 + (size_t)s_l * 64;

  f32x4 acc[4][2];
#pragma unroll
  for (int i = 0; i < 4; i++)
#pragma unroll
    for (int jj = 0; jj < 2; jj++) acc[i][jj] = {0.f, 0.f, 0.f, 0.f};

  const float* wptr = W + (size_t)(bkg * 8) * 1024 + gn0 + bnr;

  uint4 a0;
  float wb[8];
  {
    const int c0 = akg * 8;
    a0 = *reinterpret_cast<const uint4*>(abase + (size_t)(c0 >> 6) * 131072 + (c0 & 63));
  }
#pragma unroll
  for (int kk = 0; kk < 8; kk++) wb[kk] = wptr[kk * 1024];

  for (int kt = 0; kt < 1024; kt += 32) {
    const int p = (kt >> 5) & 1;
    __align__(16) bf16 bb[8];
#pragma unroll
    for (int i = 0; i < 8; i++) bb[i] = __float2bfloat16(wb[i]);
    *reinterpret_cast<uint4*>(&As[p][am][swz8(am, akg)])   = a0;
    *reinterpret_cast<uint4*>(&Bs[p][bnr][swz8(bnr, bkg)]) = *reinterpret_cast<const uint4*>(bb);
    if (kt + 32 < 1024) {            // prefetch next K-slice
      const int c0 = kt + 32 + akg * 8;
      a0 = *reinterpret_cast<const uint4*>(abase + (size_t)(c0 >> 6) * 131072 + (c0 & 63));
      wptr += 32 * 1024;
#pragma unroll
      for (int kk = 0; kk < 8; kk++) wb[kk] = wptr[kk * 1024];
    }
    __syncthreads();                 // single barrier: buf[p] writes visible

    bf16x8 af[4], bfr[2];
#pragma unroll
    for (int mt = 0; mt < 4; mt++) {
      const int r_ = wr * 64 + mt * 16 + l15;
      af[mt] = *reinterpret_cast<const bf16x8*>(&As[p][r_][swz8(r_, g)]);
    }
#pragma unroll
    for (int nt = 0; nt < 2; nt++) {
      const int r_ = wc * 32 + nt * 16 + l15;
      bfr[nt] = *reinterpret_cast<const bf16x8*>(&Bs[p][r_][swz8(r_, g)]);
    }
#pragma unroll
    for (int mt = 0; mt < 4; mt++)
#pragma unroll
      for (int nt = 0; nt < 2; nt++)
        acc[mt][nt] = __builtin_amdgcn_mfma_f32_16x16x32_bf16(af[mt], bfr[nt], acc[mt][nt], 0, 0, 0);
  }

#pragma unroll
  for (int nt = 0; nt < 2; nt++) {
    const int gc = gn0 + wc * 32 + nt * 16 + l15;
    const float bvs = bias[gc];
#pragma unroll
    for (int mt = 0; mt < 4; mt++)
#pragma unroll
      for (int r = 0; r < 4; r++) {
        const int gr = gm0 + wr * 64 + mt * 16 + g * 4 + r;
        out[(size_t)gr * 1024 + gc] = acc[mt][nt][r] + bvs;
      }
  }
}

extern "C" void kernel_launch(void* const* d_in, const int* in_sizes, int n_in,
                              void* d_out, int out_size, void* d_ws, size_t ws_size,
                              hipStream_t stream)
{
  const float *x = nullptr, *W_attn = nullptr, *b_attn = nullptr,
              *W_proj = nullptr, *b_proj = nullptr;
  for (int i = 0; i < n_in; i++) {
    switch (in_sizes[i]) {
      case 8388608: x      = (const float*)d_in[i]; break;  // [4,2048,1024]
      case 3145728: W_attn = (const float*)d_in[i]; break;  // [1024,3072]
      case 3072:    b_attn = (const float*)d_in[i]; break;
      case 1048576: W_proj = (const float*)d_in[i]; break;  // [1024,1024]
      case 1024:    b_proj = (const float*)d_in[i]; break;
      default: break;
    }
  }
  if (!x || !W_attn || !b_attn || !W_proj || !b_proj) {
    x = (const float*)d_in[0]; W_attn = (const float*)d_in[1];
    b_attn = (const float*)d_in[2]; W_proj = (const float*)d_in[3];
    b_proj = (const float*)d_in[4];
  }
  float* out = (float*)d_out;        // 8388608 f32 = 32 MiB

  // Memory plan (inputs never written; ws requirement 16 MiB):
  //   Q -> ws[0:16M)  bf16 BHSD, pre-scaled by 0.125 (later overwritten by O)
  //   K -> d_out bytes [0:16M)  bf16 BHSD   } dead before proj's f32 writes
  //   V -> d_out bytes [16M:32M) bf16 BHDS  }  (transposed for MFMA PV)
  const size_t NE = 8388608;         // bf16 elements per 16 MiB tensor
  bf16* qb = (bf16*)d_ws;
  bf16* kb = (bf16*)d_out;
  bf16* vb = kb + NE;

  qkv_f <<<dim3(1536), 512, 0, stream>>>(x, W_attn, b_attn, qb, kb, vb);
  attn_f<<<dim3(1024), 256, 0, stream>>>(qb, kb, vb);
  proj_f<<<dim3(512), 512, 0, stream>>>(qb, W_proj, b_proj, out);
}

// Round 8
// 205.175 us; speedup vs baseline: 11.5909x; 1.0379x over previous
//
#include <hip/hip_runtime.h>
#include <hip/hip_bf16.h>

typedef __hip_bfloat16 bf16;
#define NEG_BIG (-3.0e38f)

// MFMA fragment types (gfx950: v_mfma_f32_16x16x32_bf16 takes <8 x bfloat>)
typedef __bf16 bf16x8 __attribute__((ext_vector_type(8)));
typedef float  f32x4  __attribute__((ext_vector_type(4)));

__device__ inline void load8_f32(const float* p, float* o) {
  float4 a = *reinterpret_cast<const float4*>(p);
  float4 b = *reinterpret_cast<const float4*>(p + 4);
  o[0]=a.x; o[1]=a.y; o[2]=a.z; o[3]=a.w;
  o[4]=b.x; o[5]=b.y; o[6]=b.z; o[7]=b.w;
}

// k-granule XOR swizzle: breaks the 8-way bank conflict of n-row b128 writes
// at row-stride 80B. Element offset of 8-elem granule kg within a row.
// Rows r and r+8/16/24 share banks at stride 80B; XOR of (r>>3)&3 rotates
// their granules to distinct 16B slots; r vs r+32 is 2-way (free, m136).
__device__ inline int swz8(int row, int kg) { return ((kg ^ ((row >> 3) & 3)) << 3); }

// ---------- Kernel 1: QKV GEMM via MFMA, 256x128 tile, 16 waves, dbuf ----------
// X[8192,1024]f32 @ W[1024,3072]f32 + b.  BM=256 BN=128 BK=32, 1024 threads,
// 16 waves 4x4 (64x32/wave, acc[4][2] unchanged from the proven 8-wave body).
// Per-thread staging: A 8 f32 (2 dwordx4) + B 4 f32 (4 dword) = 6 VMEM,
// 12 cvt, 1 b128 + 1 b64 LDS write. Staged bytes/output -25% vs 128x128.
// Flat grid 768; decode: xcd=f&7, bm=xcd*4+(j&3), bn=j>>2 -> per-XCD X slice
// = 4 x 1MB = one L2. LDS 60KB dbuf -> 2 blocks/CU (thread-capped), single
// barrier per K-step (dbuf: re-write of buf[p] at i+2 ordered by i+1 barrier).
// Q is stored PRE-SCALED by 1/sqrt(HEAD_DIM)=0.125 (folded out of attention).
// Q -> ws bf16 BHSD; K -> d_out[0:16M) bf16 BHSD; V -> d_out[16M:32M) bf16 BHDS.
__global__ __launch_bounds__(1024)
void qkv_f(const float* __restrict__ X, const float* __restrict__ W,
           const float* __restrict__ bias,
           bf16* __restrict__ q, bf16* __restrict__ k, bf16* __restrict__ v)
{
  __shared__ __align__(16) bf16 As[2][256][40];   // row = m, 32 k + pad
  __shared__ __align__(16) bf16 Bs[2][128][40];   // row = n, 32 k + pad
  const int t   = threadIdx.x;
  const int f   = blockIdx.x;               // 0..767
  const int xcd = f & 7, j = f >> 3;        // j 0..95
  const int bm  = xcd * 4 + (j & 3);        // 0..31
  const int bn  = j >> 2;                   // 0..23
  const int gm0 = bm * 256, gn0 = bn * 128;
  const int w    = t >> 6, lane = t & 63;
  const int g    = lane >> 4, l15 = lane & 15;
  const int wr   = w >> 2, wc = w & 3;      // 4x4 wave grid -> wave tile 64x32

  const int am  = t >> 2, akg = t & 3;      // A staging: row am (0..255), granule akg
  const int bnr = t & 127, kg4 = t >> 7;    // B staging: row bnr, 4-elem k-quad kg4 (0..7)

  f32x4 acc[4][2];
#pragma unroll
  for (int i = 0; i < 4; i++)
#pragma unroll
    for (int jj = 0; jj < 2; jj++) acc[i][jj] = {0.f, 0.f, 0.f, 0.f};

  const float* aptr = X + (size_t)(gm0 + am) * 1024 + akg * 8;
  const float* wptr = W + (size_t)(kg4 * 4) * 3072 + gn0 + bnr;

  float a32[8], wb[4];
  load8_f32(aptr, a32);
#pragma unroll
  for (int kk = 0; kk < 4; kk++) wb[kk] = wptr[kk * 3072];

  for (int kt = 0; kt < 1024; kt += 32) {
    const int p = (kt >> 5) & 1;
    __align__(16) bf16 ab[8];
    __align__(8)  bf16 bb[4];
#pragma unroll
    for (int i = 0; i < 8; i++) ab[i] = __float2bfloat16(a32[i]);
#pragma unroll
    for (int i = 0; i < 4; i++) bb[i] = __float2bfloat16(wb[i]);
    *reinterpret_cast<uint4*>(&As[p][am][swz8(am, akg)]) = *reinterpret_cast<const uint4*>(ab);
    *reinterpret_cast<uint2*>(&Bs[p][bnr][swz8(bnr, kg4 >> 1) + (kg4 & 1) * 4]) =
        *reinterpret_cast<const uint2*>(bb);
    if (kt + 32 < 1024) {            // prefetch next K-slice (hides under MFMA)
      aptr += 32; wptr += 32 * 3072;
      load8_f32(aptr, a32);
#pragma unroll
      for (int kk = 0; kk < 4; kk++) wb[kk] = wptr[kk * 3072];
    }
    __syncthreads();                 // single barrier: buf[p] writes visible

    bf16x8 af[4], bfr[2];
#pragma unroll
    for (int mt = 0; mt < 4; mt++) {
      const int r_ = wr * 64 + mt * 16 + l15;
      af[mt] = *reinterpret_cast<const bf16x8*>(&As[p][r_][swz8(r_, g)]);
    }
#pragma unroll
    for (int nt = 0; nt < 2; nt++) {
      const int r_ = wc * 32 + nt * 16 + l15;
      bfr[nt] = *reinterpret_cast<const bf16x8*>(&Bs[p][r_][swz8(r_, g)]);
    }
#pragma unroll
    for (int mt = 0; mt < 4; mt++)
#pragma unroll
      for (int nt = 0; nt < 2; nt++)
        acc[mt][nt] = __builtin_amdgcn_mfma_f32_16x16x32_bf16(af[mt], bfr[nt], acc[mt][nt], 0, 0, 0);
  }

  // Epilogue: C layout row = g*4+r, col = l15. Scatter to Q/K/V (V transposed).
#pragma unroll
  for (int nt = 0; nt < 2; nt++) {
    const int gc  = gn0 + wc * 32 + nt * 16 + l15;   // never crosses Q/K/V or head boundary
    const float bvs = bias[gc];
    const int which = gc >> 10;
    const int cc = gc & 1023;
    const int hh = cc >> 6, d = cc & 63;
    bf16* dst = (which == 0) ? q : ((which == 1) ? k : v);
#pragma unroll
    for (int mt = 0; mt < 4; mt++)
#pragma unroll
      for (int r = 0; r < 4; r++) {
        const int gr = gm0 + wr * 64 + mt * 16 + g * 4 + r;
        const int bb2 = gr >> 11, s = gr & 2047;
        float val = acc[mt][nt][r] + bvs;
        if (which == 0) val *= 0.125f;   // fold softmax scale into Q
        if (which == 2)
          dst[((size_t)(bb2 * 16 + hh) * 64 + d) * 2048 + s] = __float2bfloat16(val);
        else
          dst[((size_t)(bb2 * 16 + hh) * 2048 + s) * 64 + d] = __float2bfloat16(val);
      }
  }
}

// ---------- Kernel 2: causal flash attention via MFMA, swapped QK^T ----------
// Triangular-paired + XCD-local grid: 1024 blocks (all co-resident, 4/CU).
// Block = (hb pair, qt0); processes q-tile 31-qt0 then qt0 => exactly 34
// KV-tiles per block (perfect balance). Decode puts the 16 blocks of each
// (b,h) on ONE XCD (hb = (f&7) + 8*(f>>7)) so that XCD's L2 working set is
// 8 heads x 512KB = 4MB: K/V re-reads become L2 hits instead of HBM/L3.
// Per-wave body: swapped mfma(K,Q), in-lane softmax, reg prefetch.
__global__ __launch_bounds__(256)
void attn_f(bf16* __restrict__ qo, const bf16* __restrict__ k, const bf16* __restrict__ v)
{
  __shared__ __align__(16) bf16 Ks[64][72];     // K tile, row = k, col = d
  __shared__ __align__(16) bf16 Vt[64][72];     // V tile, row = d, col = k
  __shared__ __align__(16) bf16 Ps[4][16][72];  // per-wave P, row = q, col = k

  const int t    = threadIdx.x;
  const int f    = blockIdx.x;            // 0..1023
  const int xcd  = f & 7;
  const int j    = f >> 3;                // 0..127
  const int hb   = xcd + 8 * (j >> 4);    // 0..63, fixed per XCD
  const int qt0  = j & 15;                // 0..15
  const int b    = hb >> 4, h = hb & 15;
  const size_t basebh = (size_t)(b * 16 + h) * 2048 * 64;

  const int w    = t >> 6;
  const int lane = t & 63;
  const int g    = lane >> 4;
  const int l15  = lane & 15;

  const int sr = t >> 3;          // staging row 0..31
  const int sc = (t & 7) * 8;     // staging col (elements)
  const bf16* kbase = k + basebh;
  const bf16* vbase = v + basebh;

#pragma unroll 1
  for (int pass = 0; pass < 2; ++pass) {
    const int qt = pass ? qt0 : (31 - qt0);
    const int qb = qt * 64 + w * 16;

    // Q B-fragments for this pass (operand order in mfma is swapped)
    const bf16* qrow = qo + basebh + (size_t)(qb + l15) * 64;
    bf16x8 qf0 = *reinterpret_cast<const bf16x8*>(qrow + g * 8);
    bf16x8 qf1 = *reinterpret_cast<const bf16x8*>(qrow + 32 + g * 8);

    f32x4 acc[4] = {{0,0,0,0},{0,0,0,0},{0,0,0,0},{0,0,0,0}};
    float m_run = NEG_BIG, l_run = 0.f;   // canonical per-lane q = qb + l15

    uint4 kreg0, kreg1, vreg0, vreg1;
    {
      kreg0 = *reinterpret_cast<const uint4*>(kbase + (size_t)(sr) * 64 + sc);
      kreg1 = *reinterpret_cast<const uint4*>(kbase + (size_t)(32 + sr) * 64 + sc);
      vreg0 = *reinterpret_cast<const uint4*>(vbase + (size_t)sr * 2048 + sc);
      vreg1 = *reinterpret_cast<const uint4*>(vbase + (size_t)(32 + sr) * 2048 + sc);
    }

    for (int ct = 0; ct <= qt; ++ct) {
      const int kv0 = ct * 64;
      __syncthreads();              // all waves done reading previous tile
      *reinterpret_cast<uint4*>(&Ks[sr][sc])      = kreg0;
      *reinterpret_cast<uint4*>(&Ks[32 + sr][sc]) = kreg1;
      *reinterpret_cast<uint4*>(&Vt[sr][sc])      = vreg0;
      *reinterpret_cast<uint4*>(&Vt[32 + sr][sc]) = vreg1;
      if (ct < qt) {                // prefetch next tile (hides under compute)
        const int nv0 = kv0 + 64;
        kreg0 = *reinterpret_cast<const uint4*>(kbase + (size_t)(nv0 + sr) * 64 + sc);
        kreg1 = *reinterpret_cast<const uint4*>(kbase + (size_t)(nv0 + 32 + sr) * 64 + sc);
        vreg0 = *reinterpret_cast<const uint4*>(vbase + (size_t)sr * 2048 + nv0 + sc);
        vreg1 = *reinterpret_cast<const uint4*>(vbase + (size_t)(32 + sr) * 2048 + nv0 + sc);
      }
      __syncthreads();

      // ---- S^T tile: st[kt][r] = S[k = kv0+kt*16+g*4+r][q = qb+l15] ----
      f32x4 st[4];
#pragma unroll
      for (int kt = 0; kt < 4; ++kt) {
        const int kr = kt * 16 + l15;
        bf16x8 kf0 = *reinterpret_cast<const bf16x8*>(&Ks[kr][g * 8]);
        bf16x8 kf1 = *reinterpret_cast<const bf16x8*>(&Ks[kr][32 + g * 8]);
        f32x4 c4 = {0,0,0,0};
        c4 = __builtin_amdgcn_mfma_f32_16x16x32_bf16(kf0, qf0, c4, 0, 0, 0);
        c4 = __builtin_amdgcn_mfma_f32_16x16x32_bf16(kf1, qf1, c4, 0, 0, 0);
        st[kt] = c4;
      }
      if (ct == qt) {               // causal mask, diagonal tile only
        const int qg = qb + l15;
#pragma unroll
        for (int kt = 0; kt < 4; ++kt)
#pragma unroll
          for (int r = 0; r < 4; ++r)
            if (kv0 + kt * 16 + g * 4 + r > qg) st[kt][r] = NEG_BIG;
      }

      // ---- online softmax: in-lane reduce + cross-group (masks 16,32) ----
      float mc = NEG_BIG;
#pragma unroll
      for (int kt = 0; kt < 4; ++kt)
#pragma unroll
        for (int r = 0; r < 4; ++r) mc = fmaxf(mc, st[kt][r]);
      mc = fmaxf(mc, __shfl_xor(mc, 16));
      mc = fmaxf(mc, __shfl_xor(mc, 32));
      const float mn = fmaxf(m_run, mc);
      const float alpha = __expf(m_run - mn);
      m_run = mn;
      float ps = 0.f;
#pragma unroll
      for (int kt = 0; kt < 4; ++kt)
#pragma unroll
        for (int r = 0; r < 4; ++r) {
          const float pv = __expf(st[kt][r] - mn);
          st[kt][r] = pv;
          ps += pv;
        }
      ps += __shfl_xor(ps, 16);
      ps += __shfl_xor(ps, 32);
      l_run = l_run * alpha + ps;

      // redistribute alpha (held per q=l15) to accumulator layout (q=g*4+r)
#pragma unroll
      for (int r = 0; r < 4; ++r) {
        const float ar = __shfl(alpha, g * 4 + r, 64);
#pragma unroll
        for (int dt = 0; dt < 4; ++dt) acc[dt][r] *= ar;
      }

      // ---- P -> per-wave LDS, packed b64 (4 bf16 per write) ----
#pragma unroll
      for (int kt = 0; kt < 4; ++kt) {
        union { bf16 hh[4]; uint2 u; } pk;
        pk.hh[0] = __float2bfloat16(st[kt][0]);
        pk.hh[1] = __float2bfloat16(st[kt][1]);
        pk.hh[2] = __float2bfloat16(st[kt][2]);
        pk.hh[3] = __float2bfloat16(st[kt][3]);
        *reinterpret_cast<uint2*>(&Ps[w][l15][kt * 16 + g * 4]) = pk.u;
      }
      __builtin_amdgcn_sched_barrier(0);

      // ---- O += P V  (A = P rows=q, B = V^T rows=d) ----
#pragma unroll
      for (int kc = 0; kc < 2; ++kc) {
        bf16x8 pf = *reinterpret_cast<const bf16x8*>(&Ps[w][l15][kc * 32 + g * 8]);
#pragma unroll
        for (int dt = 0; dt < 4; ++dt) {
          bf16x8 vf = *reinterpret_cast<const bf16x8*>(&Vt[dt * 16 + l15][kc * 32 + g * 8]);
          acc[dt] = __builtin_amdgcn_mfma_f32_16x16x32_bf16(pf, vf, acc[dt], 0, 0, 0);
        }
      }
    }

    // ---- epilogue: O = acc / l, in-place over this pass's Q slab ----
    const float linv = 1.f / l_run;            // for q = qb + l15
    float inv[4];
#pragma unroll
    for (int r = 0; r < 4; ++r) inv[r] = __shfl(linv, g * 4 + r, 64);
    bf16* op = qo + basebh;
#pragma unroll
    for (int dt = 0; dt < 4; ++dt)
#pragma unroll
      for (int r = 0; r < 4; ++r)
        op[(size_t)(qb + g * 4 + r) * 64 + dt * 16 + l15] =
            __float2bfloat16(acc[dt][r] * inv[r]);
  }
}

// ---------- Kernel 3: projection via MFMA, 256x128 tile, 16 waves, dbuf ----------
// A = O bf16 BHSD (ws), already bf16 -> raw b128 staging (no cvt).
// W_proj f32 -> bf16 staged transposed, out f32 [8192,1024].
// Grid 256 = exactly 1 block/CU: single fully-resident round, zero churn.
__global__ __launch_bounds__(1024)
void proj_f(const bf16* __restrict__ A, const float* __restrict__ W,
            const float* __restrict__ bias, float* __restrict__ out)
{
  __shared__ __align__(16) bf16 As[2][256][40];
  __shared__ __align__(16) bf16 Bs[2][128][40];
  const int t   = threadIdx.x;
  const int f   = blockIdx.x;               // 0..255
  const int xcd = f & 7, j = f >> 3;        // j 0..31
  const int bm  = xcd * 4 + (j & 3);        // 0..31
  const int bn  = j >> 2;                   // 0..7
  const int gm0 = bm * 256, gn0 = bn * 128;
  const int w    = t >> 6, lane = t & 63;
  const int g    = lane >> 4, l15 = lane & 15;
  const int wr   = w >> 2, wc = w & 3;      // 4x4 wave grid -> wave tile 64x32

  const int am  = t >> 2, akg = t & 3;
  const int bnr = t & 127, kg4 = t >> 7;

  const int gr_l = gm0 + am;
  const int bb_l = gr_l >> 11, s_l = gr_l & 2047;
  const bf16* abase = A + (size_t)bb_l * 2097152 + (size_t)s_l * 64;

  f32x4 acc[4][2];
#pragma unroll
  for (int i = 0; i < 4; i++)
#pragma unroll
    for (int jj = 0; jj < 2; jj++) acc[i][jj] = {0.f, 0.f, 0.f, 0.f};

  const float* wptr = W + (size_t)(kg4 * 4) * 1024 + gn0 + bnr;

  uint4 a0;
  float wb[4];
  {
    const int c0 = akg * 8;
    a0 = *reinterpret_cast<const uint4*>(abase + (size_t)(c0 >> 6) * 131072 + (c0 & 63));
  }
#pragma unroll
  for (int kk = 0; kk < 4; kk++) wb[kk] = wptr[kk * 1024];

  for (int kt = 0; kt < 1024; kt += 32) {
    const int p = (kt >> 5) & 1;
    __align__(8) bf16 bb[4];
#pragma unroll
    for (int i = 0; i < 4; i++) bb[i] = __float2bfloat16(wb[i]);
    *reinterpret_cast<uint4*>(&As[p][am][swz8(am, akg)]) = a0;
    *reinterpret_cast<uint2*>(&Bs[p][bnr][swz8(bnr, kg4 >> 1) + (kg4 & 1) * 4]) =
        *reinterpret_cast<const uint2*>(bb);
    if (kt + 32 < 1024) {            // prefetch next K-slice
      const int c0 = kt + 32 + akg * 8;
      a0 = *reinterpret_cast<const uint4*>(abase + (size_t)(c0 >> 6) * 131072 + (c0 & 63));
      wptr += 32 * 1024;
#pragma unroll
      for (int kk = 0; kk < 4; kk++) wb[kk] = wptr[kk * 1024];
    }
    __syncthreads();                 // single barrier: buf[p] writes visible

    bf16x8 af[4], bfr[2];
#pragma unroll
    for (int mt = 0; mt < 4; mt++) {
      const int r_ = wr * 64 + mt * 16 + l15;
      af[mt] = *reinterpret_cast<const bf16x8*>(&As[p][r_][swz8(r_, g)]);
    }
#pragma unroll
    for (int nt = 0; nt < 2; nt++) {
      const int r_ = wc * 32 + nt * 16 + l15;
      bfr[nt] = *reinterpret_cast<const bf16x8*>(&Bs[p][r_][swz8(r_, g)]);
    }
#pragma unroll
    for (int mt = 0; mt < 4; mt++)
#pragma unroll
      for (int nt = 0; nt < 2; nt++)
        acc[mt][nt] = __builtin_amdgcn_mfma_f32_16x16x32_bf16(af[mt], bfr[nt], acc[mt][nt], 0, 0, 0);
  }

#pragma unroll
  for (int nt = 0; nt < 2; nt++) {
    const int gc = gn0 + wc * 32 + nt * 16 + l15;
    const float bvs = bias[gc];
#pragma unroll
    for (int mt = 0; mt < 4; mt++)
#pragma unroll
      for (int r = 0; r < 4; r++) {
        const int gr = gm0 + wr * 64 + mt * 16 + g * 4 + r;
        out[(size_t)gr * 1024 + gc] = acc[mt][nt][r] + bvs;
      }
  }
}

extern "C" void kernel_launch(void* const* d_in, const int* in_sizes, int n_in,
                              void* d_out, int out_size, void* d_ws, size_t ws_size,
                              hipStream_t stream)
{
  const float *x = nullptr, *W_attn = nullptr, *b_attn = nullptr,
              *W_proj = nullptr, *b_proj = nullptr;
  for (int i = 0; i < n_in; i++) {
    switch (in_sizes[i]) {
      case 8388608: x      = (const float*)d_in[i]; break;  // [4,2048,1024]
      case 3145728: W_attn = (const float*)d_in[i]; break;  // [1024,3072]
      case 3072:    b_attn = (const float*)d_in[i]; break;
      case 1048576: W_proj = (const float*)d_in[i]; break;  // [1024,1024]
      case 1024:    b_proj = (const float*)d_in[i]; break;
      default: break;
    }
  }
  if (!x || !W_attn || !b_attn || !W_proj || !b_proj) {
    x = (const float*)d_in[0]; W_attn = (const float*)d_in[1];
    b_attn = (const float*)d_in[2]; W_proj = (const float*)d_in[3];
    b_proj = (const float*)d_in[4];
  }
  float* out = (float*)d_out;        // 8388608 f32 = 32 MiB

  // Memory plan (inputs never written; ws requirement 16 MiB):
  //   Q -> ws[0:16M)  bf16 BHSD, pre-scaled by 0.125 (later overwritten by O)
  //   K -> d_out bytes [0:16M)  bf16 BHSD   } dead before proj's f32 writes
  //   V -> d_out bytes [16M:32M) bf16 BHDS  }  (transposed for MFMA PV)
  const size_t NE = 8388608;         // bf16 elements per 16 MiB tensor
  bf16* qb = (bf16*)d_ws;
  bf16* kb = (bf16*)d_out;
  bf16* vb = kb + NE;

  qkv_f <<<dim3(768), 1024, 0, stream>>>(x, W_attn, b_attn, qb, kb, vb);
  attn_f<<<dim3(1024), 256, 0, stream>>>(qb, kb, vb);
  proj_f<<<dim3(256), 1024, 0, stream>>>(qb, W_proj, b_proj, out);
}